// Round 6
// baseline (8180.755 us; speedup 1.0000x reference)
//
#include <hip/hip_runtime.h>
#include <hip/hip_bf16.h>

#define NN 50000      // nodes
#define NE 800000     // edges
// C=32 channels, K=64 spline kernels, H=8 heads, DH=4, M=32 features

__device__ __forceinline__ void ldsAdd(float* p, float v) {
    __hip_atomic_fetch_add(p, v, __ATOMIC_RELAXED, __HIP_MEMORY_SCOPE_WORKGROUP);
}
__device__ __forceinline__ void gAdd(float* p, float v) {
    unsafeAtomicAdd(p, v);   // global_atomic_add_f32, no CAS loop
}
__device__ __forceinline__ unsigned short f2bf(float f) {   // RNE bf16
    unsigned u = __float_as_uint(f);
    u += 0x7FFF + ((u >> 16) & 1);
    return (unsigned short)(u >> 16);
}

// ---------------- K1: histogram of dst ----------------
__global__ void k_hist(const int* __restrict__ ei, int* __restrict__ cnt) {
    int e = blockIdx.x * 256 + threadIdx.x;   // grid exact: 3125*256 = 800000
    atomicAdd(&cnt[ei[NE + e]], 1);
}

// ---------------- K2: exclusive scan (single block, shfl-based) ----------------
__global__ void __launch_bounds__(1024) k_scan(const int* __restrict__ cnt,
                                               int* __restrict__ rowptr,
                                               int* __restrict__ fill,
                                               float* __restrict__ degf) {
    __shared__ int wsum[16];
    int tid = threadIdx.x;
    int wave = tid >> 6, lane = tid & 63;
    int carry = 0;
    for (int base = 0; base < NN; base += 8192) {
        int i0 = base + tid * 8;
        int v[8], pre[8], s = 0;
#pragma unroll
        for (int j = 0; j < 8; j++) {
            int i = i0 + j;
            v[j] = (i < NN) ? cnt[i] : 0;
            pre[j] = s; s += v[j];
        }
        int sc = s;
#pragma unroll
        for (int d = 1; d < 64; d <<= 1) {
            int t = __shfl_up(sc, d);
            if (lane >= d) sc += t;
        }
        if (lane == 63) wsum[wave] = sc;
        __syncthreads();
        int wpre = 0, total = 0;
#pragma unroll
        for (int w = 0; w < 16; w++) {
            int x = wsum[w];
            if (w < wave) wpre += x;
            total += x;
        }
        int excl = carry + wpre + (sc - s);
#pragma unroll
        for (int j = 0; j < 8; j++) {
            int i = i0 + j;
            if (i < NN) {
                int st = excl + pre[j];
                rowptr[i] = st;
                fill[i]   = st;
                degf[i]   = (float)(v[j] > 0 ? v[j] : 1);
                if (i == NN - 1) rowptr[NN] = st + v[j];
            }
        }
        carry += total;
        __syncthreads();
    }
}

// ---------------- K3: scatter edges into CSR order (+rel edge table) ----------------
__global__ void k_scatter(const int* __restrict__ ei, const float* __restrict__ attr,
                          const float* __restrict__ degf,
                          int* __restrict__ fill, float4* __restrict__ sedge,
                          float2* __restrict__ re2) {
    int e = blockIdx.x * 256 + threadIdx.x;
    int src = ei[e], dst = ei[NE + e];
    int pos = atomicAdd(&fill[dst], 1);
    float4 r;
    r.x = __int_as_float(src);
    r.y = attr[e * 3 + 0]; r.z = attr[e * 3 + 1]; r.w = attr[e * 3 + 2];
    sedge[pos] = r;
    re2[pos] = make_float2(__int_as_float(src), rsqrtf(degf[src] * degf[dst]));
}

// ---------------- K3b: fp32 -> bf16 row copy ----------------
__global__ void k_cvt(const float* __restrict__ xin, unsigned short* __restrict__ xh) {
    int i = blockIdx.x * 256 + threadIdx.x;   // grid exact: NN*32/256
    xh[i] = f2bf(xin[i]);
}

// ---------------- K4: fused SplineConv + leaky + BN-stats ----------------
// 4 nodes/block, 256 threads. LDS buf layout: [idx(64)][t(4)][c ^ ((idx&7)<<2)]
__device__ __forceinline__ void edge_proc2(float* __restrict__ buf,
                                           float ay, float az, float aw, int t,
                                           float xs, int ch, int hi) {
    float p0 = ay * 3.f, p1 = az * 3.f, p2 = aw * 3.f;
    float f0 = fmaxf(fminf(floorf(p0), 2.f), 0.f);
    float f1 = fmaxf(fminf(floorf(p1), 2.f), 0.f);
    float f2 = fmaxf(fminf(floorf(p2), 2.f), 0.f);
    float r0 = p0 - f0, r1 = p1 - f1, r2 = p2 - f2;
    int i0 = (int)f0, i1 = (int)f1, i2 = (int)f2;
#pragma unroll
    for (int q = 0; q < 4; q++) {
        int bits = hi * 4 + q;
        int b0 = bits & 1, b1 = (bits >> 1) & 1, b2 = (bits >> 2) & 1;
        float bas = (b0 ? r0 : 1.f - r0) * (b1 ? r1 : 1.f - r1) * (b2 ? r2 : 1.f - r2);
        int idx = (i0 + b0) + 4 * (i1 + b1) + 16 * (i2 + b2);
        ldsAdd(&buf[((idx * 4 + t) << 5) + (ch ^ ((idx & 7) << 2))], bas * xs);
    }
}

__global__ void __launch_bounds__(256) k_spline(
        const float* __restrict__ xin, const unsigned short* __restrict__ xh,
        const int* __restrict__ rowptr,
        const float4* __restrict__ sedge, const float* __restrict__ degf,
        const float* __restrict__ wsp, const float* __restrict__ root,
        const float* __restrict__ bias, float* __restrict__ out,
        float* __restrict__ stats) {
    __shared__ __align__(16) float buf[8192];   // 64k * 4t * 32c = 32 KB
    __shared__ __align__(16) float xt[4][32];
    __shared__ __align__(16) float scr[1024];   // [wave*2+hf (8)][d8(8)][t(4)][4]
    __shared__ float scr2[64];
    int tid = threadIdx.x;
    int wave = tid >> 6, lane = tid & 63;
    for (int i = tid; i < 8192; i += 256) buf[i] = 0.f;
    if (tid < 64) scr2[tid] = 0.f;
    int nb = blockIdx.x * 4;                    // NN % 4 == 0
    if (tid < 128) {
        int t = tid >> 5, c = tid & 31;
        xt[t][c] = xin[(nb + t) * 32 + c];
    }
    __syncthreads();
    // -------- phase A: wave w owns node nb+w; coalesced edge sweep + shfl + 8-deep gather --------
    {
        int n = nb + wave;
        int rs = rowptr[n], re = rowptr[n + 1];
        int ch = lane & 31, hi = lane >> 5;
        for (int ce = rs; ce < re; ce += 64) {
            int cnt = re - ce; if (cnt > 64) cnt = 64;
            float4 myed = make_float4(0.f, 0.f, 0.f, 0.f);
            if (lane < cnt) myed = sedge[ce + lane];
            int mysrc = __float_as_int(myed.x);
            for (int j0 = 0; j0 < cnt; j0 += 8) {
                float xsv[8], ey[8], ez[8], ew[8];
#pragma unroll
                for (int jj = 0; jj < 8; jj++) {
                    int j = j0 + jj;
                    int s  = __shfl(mysrc, j);
                    ey[jj] = __shfl(myed.y, j);
                    ez[jj] = __shfl(myed.z, j);
                    ew[jj] = __shfl(myed.w, j);
                    int sc = (j < cnt) ? s : 0;
                    unsigned short u = xh[sc * 32 + ch];   // bf16 row gather (64B line)
                    xsv[jj] = __uint_as_float(((unsigned)u) << 16);
                }
#pragma unroll
                for (int jj = 0; jj < 8; jj++) {
                    int j = j0 + jj;
                    if (j < cnt)
                        edge_proc2(buf, ey[jj], ez[jj], ew[jj], wave, xsv[jj], ch, hi);
                }
            }
        }
    }
    __syncthreads();
    // -------- phase B: einsum nkc,kcd -> nd ; k = hf*32 + wave*8 + kk --------
    int kk = lane >> 3, d8 = lane & 7;
    float4 acc[2][4];
#pragma unroll
    for (int hf = 0; hf < 2; hf++)
#pragma unroll
        for (int t = 0; t < 4; t++) acc[hf][t] = make_float4(0.f, 0.f, 0.f, 0.f);
#pragma unroll
    for (int hf = 0; hf < 2; hf++) {
        int k = hf * 32 + wave * 8 + kk;        // k&7 == kk
        const float* wk = wsp + k * 1024;
#pragma unroll
        for (int c4 = 0; c4 < 8; c4++) {
            float4 wv0 = *(const float4*)(wk + (c4 * 4 + 0) * 32 + d8 * 4);
            float4 wv1 = *(const float4*)(wk + (c4 * 4 + 1) * 32 + d8 * 4);
            float4 wv2 = *(const float4*)(wk + (c4 * 4 + 2) * 32 + d8 * 4);
            float4 wv3 = *(const float4*)(wk + (c4 * 4 + 3) * 32 + d8 * 4);
            int cp = (c4 ^ kk) << 2;
            const float* bp = &buf[(k * 4) << 5];
#pragma unroll
            for (int t = 0; t < 4; t++) {
                float4 bv = *(const float4*)(bp + (t << 5) + cp);
                acc[hf][t].x += bv.x * wv0.x + bv.y * wv1.x + bv.z * wv2.x + bv.w * wv3.x;
                acc[hf][t].y += bv.x * wv0.y + bv.y * wv1.y + bv.z * wv2.y + bv.w * wv3.y;
                acc[hf][t].z += bv.x * wv0.z + bv.y * wv1.z + bv.z * wv2.z + bv.w * wv3.z;
                acc[hf][t].w += bv.x * wv0.w + bv.y * wv1.w + bv.z * wv2.w + bv.w * wv3.w;
            }
        }
    }
#pragma unroll
    for (int hf = 0; hf < 2; hf++)
#pragma unroll
    for (int t = 0; t < 4; t++) {
        float sx = acc[hf][t].x, sy = acc[hf][t].y, sz = acc[hf][t].z, sw = acc[hf][t].w;
        sx += __shfl_xor(sx, 8);  sy += __shfl_xor(sy, 8);  sz += __shfl_xor(sz, 8);  sw += __shfl_xor(sw, 8);
        sx += __shfl_xor(sx, 16); sy += __shfl_xor(sy, 16); sz += __shfl_xor(sz, 16); sw += __shfl_xor(sw, 16);
        sx += __shfl_xor(sx, 32); sy += __shfl_xor(sy, 32); sz += __shfl_xor(sz, 32); sw += __shfl_xor(sw, 32);
        acc[hf][t] = make_float4(sx, sy, sz, sw);
    }
    if (kk == 0) {
#pragma unroll
        for (int hf = 0; hf < 2; hf++)
#pragma unroll
        for (int t = 0; t < 4; t++)
            *(float4*)&scr[(wave * 2 + hf) * 128 + d8 * 16 + t * 4] = acc[hf][t];
    }
    __syncthreads();
    if (tid < 128) {
        int t = tid >> 5, d = tid & 31;
        int n = nb + t;
        float v = 0.f;
#pragma unroll
        for (int wh = 0; wh < 8; wh++)
            v += scr[wh * 128 + (d >> 2) * 16 + t * 4 + (d & 3)];
        v /= degf[n];
        float rt = 0.f;
#pragma unroll
        for (int c = 0; c < 32; c++) rt += xt[t][c] * root[c * 32 + d];
        v += rt + bias[d];
        v = v >= 0.f ? v : 0.01f * v;   // LeakyReLU (both spline layers)
        out[n * 32 + d] = v;
        float s = v, s2 = v * v;
        s += __shfl_xor(s, 32); s2 += __shfl_xor(s2, 32);
        if ((tid & 63) < 32) { ldsAdd(&scr2[d], s); ldsAdd(&scr2[32 + d], s2); }
    }
    __syncthreads();
    // replicated stats: spreads atomics over 64 slots (no hot lines)
    if (tid < 64) gAdd(&stats[(blockIdx.x & 63) * 64 + tid], scr2[tid]);
}

// ================= ABLATION KERNELS (write only to scratch; appended at end) =================
// k_abl_g: phase-A gather path only (sedge sweep + shfls + xh gather), R=6
__global__ void __launch_bounds__(256) k_abl_g(
        const unsigned short* __restrict__ xh, const int* __restrict__ rowptr,
        const float4* __restrict__ sedge, float* __restrict__ scratch) {
    int tid = threadIdx.x;
    int wave = tid >> 6, lane = tid & 63;
    int nb = blockIdx.x * 4;
    int n = nb + wave;
    int ch = lane & 31;
    float acc = 0.f;
    for (int rep = 0; rep < 6; rep++) {
        int rs = rowptr[n], re = rowptr[n + 1];
        for (int ce = rs; ce < re; ce += 64) {
            int cnt = re - ce; if (cnt > 64) cnt = 64;
            float4 myed = make_float4(0.f, 0.f, 0.f, 0.f);
            if (lane < cnt) myed = sedge[ce + lane];
            int mysrc = __float_as_int(myed.x);
            for (int j0 = 0; j0 < cnt; j0 += 8) {
                float xsv[8];
#pragma unroll
                for (int jj = 0; jj < 8; jj++) {
                    int j = j0 + jj;
                    int s  = __shfl(mysrc, j);
                    float a = __shfl(myed.y, j);
                    float b = __shfl(myed.z, j);
                    float c = __shfl(myed.w, j);
                    asm volatile("" :: "v"(a), "v"(b), "v"(c));
                    int sc = (j < cnt) ? s : 0;
                    unsigned short u = xh[sc * 32 + ch];
                    xsv[jj] = __uint_as_float(((unsigned)u) << 16);
                    asm volatile("" :: "v"(xsv[jj]));
                }
                acc += xsv[0];
            }
        }
    }
    if (tid == 0) scratch[blockIdx.x & 4095] = acc;
}

// k_abl_a: full phase A (gather + basis VALU + LDS atomics), R=3
__global__ void __launch_bounds__(256) k_abl_a(
        const unsigned short* __restrict__ xh, const int* __restrict__ rowptr,
        const float4* __restrict__ sedge, float* __restrict__ scratch) {
    __shared__ __align__(16) float buf[8192];
    int tid = threadIdx.x;
    int wave = tid >> 6, lane = tid & 63;
    for (int i = tid; i < 8192; i += 256) buf[i] = 0.f;
    int nb = blockIdx.x * 4;
    __syncthreads();
    int n = nb + wave;
    int ch = lane & 31, hi = lane >> 5;
    for (int rep = 0; rep < 3; rep++) {
        int rs = rowptr[n], re = rowptr[n + 1];
        for (int ce = rs; ce < re; ce += 64) {
            int cnt = re - ce; if (cnt > 64) cnt = 64;
            float4 myed = make_float4(0.f, 0.f, 0.f, 0.f);
            if (lane < cnt) myed = sedge[ce + lane];
            int mysrc = __float_as_int(myed.x);
            for (int j0 = 0; j0 < cnt; j0 += 8) {
                float xsv[8], ey[8], ez[8], ew[8];
#pragma unroll
                for (int jj = 0; jj < 8; jj++) {
                    int j = j0 + jj;
                    int s  = __shfl(mysrc, j);
                    ey[jj] = __shfl(myed.y, j);
                    ez[jj] = __shfl(myed.z, j);
                    ew[jj] = __shfl(myed.w, j);
                    int sc = (j < cnt) ? s : 0;
                    unsigned short u = xh[sc * 32 + ch];
                    xsv[jj] = __uint_as_float(((unsigned)u) << 16);
                }
#pragma unroll
                for (int jj = 0; jj < 8; jj++) {
                    int j = j0 + jj;
                    if (j < cnt)
                        edge_proc2(buf, ey[jj], ez[jj], ew[jj], wave, xsv[jj], ch, hi);
                }
            }
        }
    }
    __syncthreads();
    scratch[(blockIdx.x & 4095) * 256 + tid] = buf[tid * 17 & 8191];
}

// k_abl_b: phase B einsum + reduce + epilogue only (buf zeroed), R=2
__global__ void __launch_bounds__(256) k_abl_b(
        const float* __restrict__ xin, const float* __restrict__ degf,
        const float* __restrict__ wsp, const float* __restrict__ root,
        const float* __restrict__ bias, float* __restrict__ scratch) {
    __shared__ __align__(16) float buf[8192];
    __shared__ __align__(16) float xt[4][32];
    __shared__ __align__(16) float scr[1024];
    int tid = threadIdx.x;
    int wave = tid >> 6, lane = tid & 63;
    for (int i = tid; i < 8192; i += 256) buf[i] = 0.f;
    int nb = blockIdx.x * 4;
    if (tid < 128) {
        int t = tid >> 5, c = tid & 31;
        xt[t][c] = xin[(nb + t) * 32 + c];
    }
    __syncthreads();
    for (int rep = 0; rep < 2; rep++) {
        int kk = lane >> 3, d8 = lane & 7;
        float4 acc[2][4];
#pragma unroll
        for (int hf = 0; hf < 2; hf++)
#pragma unroll
            for (int t = 0; t < 4; t++) acc[hf][t] = make_float4(0.f, 0.f, 0.f, 0.f);
#pragma unroll
        for (int hf = 0; hf < 2; hf++) {
            int k = hf * 32 + wave * 8 + kk;
            const float* wk = wsp + k * 1024;
#pragma unroll
            for (int c4 = 0; c4 < 8; c4++) {
                float4 wv0 = *(const float4*)(wk + (c4 * 4 + 0) * 32 + d8 * 4);
                float4 wv1 = *(const float4*)(wk + (c4 * 4 + 1) * 32 + d8 * 4);
                float4 wv2 = *(const float4*)(wk + (c4 * 4 + 2) * 32 + d8 * 4);
                float4 wv3 = *(const float4*)(wk + (c4 * 4 + 3) * 32 + d8 * 4);
                int cp = (c4 ^ kk) << 2;
                const float* bp = &buf[(k * 4) << 5];
#pragma unroll
                for (int t = 0; t < 4; t++) {
                    float4 bv = *(const float4*)(bp + (t << 5) + cp);
                    acc[hf][t].x += bv.x * wv0.x + bv.y * wv1.x + bv.z * wv2.x + bv.w * wv3.x;
                    acc[hf][t].y += bv.x * wv0.y + bv.y * wv1.y + bv.z * wv2.y + bv.w * wv3.y;
                    acc[hf][t].z += bv.x * wv0.z + bv.y * wv1.z + bv.z * wv2.z + bv.w * wv3.z;
                    acc[hf][t].w += bv.x * wv0.w + bv.y * wv1.w + bv.z * wv2.w + bv.w * wv3.w;
                }
            }
        }
#pragma unroll
        for (int hf = 0; hf < 2; hf++)
#pragma unroll
        for (int t = 0; t < 4; t++) {
            float sx = acc[hf][t].x, sy = acc[hf][t].y, sz = acc[hf][t].z, sw = acc[hf][t].w;
            sx += __shfl_xor(sx, 8);  sy += __shfl_xor(sy, 8);  sz += __shfl_xor(sz, 8);  sw += __shfl_xor(sw, 8);
            sx += __shfl_xor(sx, 16); sy += __shfl_xor(sy, 16); sz += __shfl_xor(sz, 16); sw += __shfl_xor(sw, 16);
            sx += __shfl_xor(sx, 32); sy += __shfl_xor(sy, 32); sz += __shfl_xor(sz, 32); sw += __shfl_xor(sw, 32);
            acc[hf][t] = make_float4(sx, sy, sz, sw);
        }
        if (kk == 0) {
#pragma unroll
            for (int hf = 0; hf < 2; hf++)
#pragma unroll
            for (int t = 0; t < 4; t++)
                *(float4*)&scr[(wave * 2 + hf) * 128 + d8 * 16 + t * 4] = acc[hf][t];
        }
        __syncthreads();
        if (tid < 128) {
            int t = tid >> 5, d = tid & 31;
            int n = nb + t;
            float v = 0.f;
#pragma unroll
            for (int wh = 0; wh < 8; wh++)
                v += scr[wh * 128 + (d >> 2) * 16 + t * 4 + (d & 3)];
            v /= degf[n];
            float rt = 0.f;
#pragma unroll
            for (int c = 0; c < 32; c++) rt += xt[t][c] * root[c * 32 + d];
            v += rt + bias[d];
            v = v >= 0.f ? v : 0.01f * v;
            scratch[n * 32 + d] = v;
        }
        __syncthreads();
    }
}

// ---------------- K4b: fold 64 replicated stat slots ----------------
__global__ void k_red(const float* __restrict__ stats, float* __restrict__ fin) {
    int j = threadIdx.x;   // 64 threads
    float s = 0.f;
#pragma unroll 8
    for (int r = 0; r < 64; r++) s += stats[r * 64 + j];
    fin[j] = s;
}

// ---------------- K5: BN apply (optionally also emit bf16 copy) ----------------
__global__ void k_bn(const float* __restrict__ tin, const float* __restrict__ fin,
                     const float* __restrict__ gamma, const float* __restrict__ beta,
                     float* __restrict__ xout) {
    int i = blockIdx.x * 256 + threadIdx.x;   // grid exact
    int c = i & 31;
    float mu = fin[c] * (1.f / NN);
    float var = fin[32 + c] * (1.f / NN) - mu * mu;
    float g = gamma[c] * rsqrtf(var + 1e-5f);
    xout[i] = (tin[i] - mu) * g + beta[c];
}
__global__ void k_bn_cvt(const float* __restrict__ tin, const float* __restrict__ fin,
                         const float* __restrict__ gamma, const float* __restrict__ beta,
                         float* __restrict__ xout, unsigned short* __restrict__ xh) {
    int i = blockIdx.x * 256 + threadIdx.x;
    int c = i & 31;
    float mu = fin[c] * (1.f / NN);
    float var = fin[32 + c] * (1.f / NN) - mu * mu;
    float g = gamma[c] * rsqrtf(var + 1e-5f);
    float v = (tin[i] - mu) * g + beta[c];
    xout[i] = v;
    xh[i] = f2bf(v);
}

// ---------------- K6a: NodeFormer pass 1 ----------------
// 32 nodes/block, 256 threads: thread = (nl = tid>>3, h = tid&7)
// kvloc layout: [dh(4)][h(8)][m(32)] at dh*256+h*32+m ; ksum at 1024+h*32+m
__global__ void __launch_bounds__(256) k_nf1(
        const float* __restrict__ x, const float* __restrict__ wqkv,
        const float* __restrict__ wp, const float* __restrict__ gumbel,
        float* __restrict__ vbuf, float* __restrict__ kvg) {
    __shared__ float xl[32 * 33];
    __shared__ float kvloc[1280];
    int tid = threadIdx.x;
    for (int i = tid; i < 1280; i += 256) kvloc[i] = 0.f;
    int base = blockIdx.x * 32;
#pragma unroll
    for (int r = 0; r < 4; r++) {
        int i = r * 256 + tid;
        int gi = base * 32 + i;
        float v = (gi < NN * 32) ? x[gi] : 0.f;
        xl[(i >> 5) * 33 + (i & 31)] = v;
    }
    __syncthreads();
    int nl = tid >> 3, h = tid & 7;
    int n = base + nl;
    int act = (n < NN) ? 1 : 0;
    const float* xp = &xl[nl * 33];
    float kr0 = 0, kr1 = 0, kr2 = 0, kr3 = 0, vr0 = 0, vr1 = 0, vr2 = 0, vr3 = 0;
#pragma unroll
    for (int c = 0; c < 32; c++) {
        float xc = xp[c];
        const float4 wk4 = *(const float4*)(wqkv + 1024 + c * 32 + h * 4);
        const float4 wv4 = *(const float4*)(wqkv + 2048 + c * 32 + h * 4);
        kr0 += xc * wk4.x; kr1 += xc * wk4.y; kr2 += xc * wk4.z; kr3 += xc * wk4.w;
        vr0 += xc * wv4.x; vr1 += xc * wv4.y; vr2 += xc * wv4.z; vr3 += xc * wv4.w;
    }
    if (act) *(float4*)&vbuf[n * 32 + h * 4] = make_float4(vr0, vr1, vr2, vr3);
    const float inv_rt2 = 0.70710678118f;     // 1/DH^0.25
    const float invSqM = 0.17677669529f;      // 1/sqrt(32)
    float x0 = kr0 * inv_rt2, x1 = kr1 * inv_rt2, x2 = kr2 * inv_rt2, x3 = kr3 * inv_rt2;
    float sq = 0.5f * (x0 * x0 + x1 * x1 + x2 * x2 + x3 * x3);
    float gs = act ? (__expf(gumbel[(act ? n : 0) * 8 + h]) * invSqM) : 0.f;
    const float* wph = wp + h * 128;
    for (int mm = 0; mm < 32; mm++) {
        int m = (mm + nl + 4 * h) & 31;       // stagger: ≤2-way LDS banks
        float pr = x0 * wph[m] + x1 * wph[32 + m] + x2 * wph[64 + m] + x3 * wph[96 + m];
        float phk = __expf(pr - sq) * gs;
        ldsAdd(&kvloc[1024 + h * 32 + m], phk);
        ldsAdd(&kvloc[0 * 256 + h * 32 + m], phk * vr0);
        ldsAdd(&kvloc[1 * 256 + h * 32 + m], phk * vr1);
        ldsAdd(&kvloc[2 * 256 + h * 32 + m], phk * vr2);
        ldsAdd(&kvloc[3 * 256 + h * 32 + m], phk * vr3);
    }
    __syncthreads();
    // replicated kvg: 8 slots
    float* kvr = kvg + (blockIdx.x & 7) * 1280;
    for (int i = tid; i < 1280; i += 256) gAdd(&kvr[i], kvloc[i]);
}

// ---------------- K6b: NodeFormer pass 2 ----------------
__global__ void __launch_bounds__(256) k_nf2(
        const float* __restrict__ x, const float* __restrict__ wqkv,
        const float* __restrict__ wp, const float* __restrict__ brel,
        const float* __restrict__ wo, const float* __restrict__ bo,
        const float* __restrict__ kvg, const int* __restrict__ rowptr,
        const float2* __restrict__ re2, const float* __restrict__ vbuf,
        int do_leaky, float* __restrict__ out, float* __restrict__ stats) {
    __shared__ float xl[32 * 33];
    __shared__ float ylds[32 * 33];
    __shared__ float kvs[1280];
    __shared__ float scr2[64];
    int tid = threadIdx.x;
    if (tid < 64) scr2[tid] = 0.f;
    int base = blockIdx.x * 32;
#pragma unroll
    for (int r = 0; r < 4; r++) {
        int i = r * 256 + tid;
        int gi = base * 32 + i;
        float v = (gi < NN * 32) ? x[gi] : 0.f;
        xl[(i >> 5) * 33 + (i & 31)] = v;
    }
    // stage kv summary: sum the 8 replicated slots into LDS
    for (int i = tid; i < 1280; i += 256) {
        float s = 0.f;
#pragma unroll
        for (int r = 0; r < 8; r++) s += kvg[r * 1280 + i];
        kvs[i] = s;
    }
    __syncthreads();
    int nl = tid >> 3, h = tid & 7;
    int n = base + nl;
    int act = (n < NN) ? 1 : 0;
    int nc = act ? n : (NN - 1);
    const float* xp = &xl[nl * 33];
    float q0 = 0, q1 = 0, q2 = 0, q3 = 0;
#pragma unroll
    for (int c = 0; c < 32; c++) {
        float xc = xp[c];
        const float4 wq4 = *(const float4*)(wqkv + c * 32 + h * 4);
        q0 += xc * wq4.x; q1 += xc * wq4.y; q2 += xc * wq4.z; q3 += xc * wq4.w;
    }
    const float inv_rt2 = 0.70710678118f;
    const float invSqM = 0.17677669529f;
    float x0 = q0 * inv_rt2, x1 = q1 * inv_rt2, x2 = q2 * inv_rt2, x3 = q3 * inv_rt2;
    float sq = 0.5f * (x0 * x0 + x1 * x1 + x2 * x2 + x3 * x3);
    const float* wph = wp + h * 128;
    float den = 0.f, n0 = 0.f, n1 = 0.f, n2 = 0.f, n3 = 0.f;
    for (int mm = 0; mm < 32; mm++) {
        int m = (mm + 4 * h) & 31;            // h-stagger: LDS bank-clean
        float pr = x0 * wph[m] + x1 * wph[32 + m] + x2 * wph[64 + m] + x3 * wph[96 + m];
        float phq = __expf(pr - sq) * invSqM;
        den += phq * kvs[1024 + h * 32 + m];
        n0 += phq * kvs[0 * 256 + h * 32 + m];
        n1 += phq * kvs[1 * 256 + h * 32 + m];
        n2 += phq * kvs[2 * 256 + h * 32 + m];
        n3 += phq * kvs[3 * 256 + h * 32 + m];
    }
    float inv = 1.f / (den + 1e-6f);
    float y0 = n0 * inv, y1 = n1 * inv, y2 = n2 * inv, y3 = n3 * inv;
    // relational bias: 8-deep shfl-batched vbuf row gathers
    float r0 = 0, r1 = 0, r2 = 0, r3 = 0;
    int rs = rowptr[nc];
    int re = act ? rowptr[nc + 1] : rs;
    int lb = (tid & 63) & 56;                 // wave-lane base of this node's 8-group
    for (int e0 = rs; e0 < re; e0 += 8) {
        int cnt = re - e0; if (cnt > 8) cnt = 8;
        float2 med = make_float2(__int_as_float(0), 0.f);
        if (h < cnt) med = re2[e0 + h];
        int msrc = __float_as_int(med.x);
        float4 xs4[8];
        float nrj[8];
#pragma unroll
        for (int jj = 0; jj < 8; jj++) {
            int s   = __shfl(msrc, lb + jj);
            float nr = __shfl(med.y, lb + jj);
            nrj[jj] = (jj < cnt) ? nr : 0.f;
            int sc  = (jj < cnt) ? s : 0;
            xs4[jj] = *(const float4*)&vbuf[sc * 32 + h * 4];
        }
#pragma unroll
        for (int jj = 0; jj < 8; jj++) {
            r0 += nrj[jj] * xs4[jj].x;
            r1 += nrj[jj] * xs4[jj].y;
            r2 += nrj[jj] * xs4[jj].z;
            r3 += nrj[jj] * xs4[jj].w;
        }
    }
    float sg = 1.f / (1.f + __expf(-brel[h]));
    y0 += sg * r0; y1 += sg * r1; y2 += sg * r2; y3 += sg * r3;
    ylds[nl * 33 + h * 4 + 0] = y0;
    ylds[nl * 33 + h * 4 + 1] = y1;
    ylds[nl * 33 + h * 4 + 2] = y2;
    ylds[nl * 33 + h * 4 + 3] = y3;
    __syncthreads();
    // output projection: thread (nl,h) computes z[d = h*4 .. h*4+3]
    const float* yp = &ylds[nl * 33];
    const float4 b4 = *(const float4*)(bo + h * 4);
    float z0 = b4.x, z1 = b4.y, z2 = b4.z, z3 = b4.w;
#pragma unroll
    for (int j = 0; j < 32; j++) {
        float yv = yp[j];
        const float4 w4 = *(const float4*)(wo + j * 32 + h * 4);
        z0 += yv * w4.x; z1 += yv * w4.y; z2 += yv * w4.z; z3 += yv * w4.w;
    }
    if (do_leaky) {
        z0 = z0 >= 0.f ? z0 : 0.01f * z0;
        z1 = z1 >= 0.f ? z1 : 0.01f * z1;
        z2 = z2 >= 0.f ? z2 : 0.01f * z2;
        z3 = z3 >= 0.f ? z3 : 0.01f * z3;
    }
    if (act) *(float4*)&out[n * 32 + h * 4] = make_float4(z0, z1, z2, z3);
    // BN stats: reduce over nl (wave lane bits 3..5), then LDS, then global
    float sv[4] = {act ? z0 : 0.f, act ? z1 : 0.f, act ? z2 : 0.f, act ? z3 : 0.f};
#pragma unroll
    for (int j = 0; j < 4; j++) {
        float s = sv[j], s2 = sv[j] * sv[j];
        s += __shfl_xor(s, 8);  s2 += __shfl_xor(s2, 8);
        s += __shfl_xor(s, 16); s2 += __shfl_xor(s2, 16);
        s += __shfl_xor(s, 32); s2 += __shfl_xor(s2, 32);
        if (((tid & 63) >> 3) == 0) {
            ldsAdd(&scr2[h * 4 + j], s);
            ldsAdd(&scr2[32 + h * 4 + j], s2);
        }
    }
    __syncthreads();
    if (tid < 64) gAdd(&stats[(blockIdx.x & 63) * 64 + tid], scr2[tid]);
}

extern "C" void kernel_launch(void* const* d_in, const int* in_sizes, int n_in,
                              void* d_out, int out_size, void* d_ws, size_t ws_size,
                              hipStream_t stream) {
    (void)in_sizes; (void)n_in; (void)out_size; (void)ws_size;
    const float* x_in  = (const float*)d_in[0];
    const int*   ei    = (const int*)d_in[1];
    const float* attr  = (const float*)d_in[2];
    const float* wsp1  = (const float*)d_in[3];
    const float* root1 = (const float*)d_in[4];
    const float* bias1 = (const float*)d_in[5];
    const float* wsp2  = (const float*)d_in[6];
    const float* root2 = (const float*)d_in[7];
    const float* bias2 = (const float*)d_in[8];
    const float* gam   = (const float*)d_in[9];
    const float* bet   = (const float*)d_in[10];
    const float* w1qkv = (const float*)d_in[11];
    const float* w1p   = (const float*)d_in[12];
    const float* b1rel = (const float*)d_in[13];
    const float* w1o   = (const float*)d_in[14];
    const float* b1o   = (const float*)d_in[15];
    const float* gum1  = (const float*)d_in[16];
    const float* w2qkv = (const float*)d_in[17];
    const float* w2p   = (const float*)d_in[18];
    const float* b2rel = (const float*)d_in[19];
    const float* w2o   = (const float*)d_in[20];
    const float* b2o   = (const float*)d_in[21];
    const float* gum2  = (const float*)d_in[22];
    float* outp = (float*)d_out;

    char* wsb = (char*)d_ws;
    size_t off = 0;
    auto carve = [&](size_t bytes) -> char* {
        char* p = wsb + off;
        off += (bytes + 255) & ~(size_t)255;
        return p;
    };
    int*    cnt    = (int*)carve((size_t)NN * 4);
    float*  kvg1   = (float*)carve(8 * 1280 * 4);
    float*  kvg2   = (float*)carve(8 * 1280 * 4);
    float*  stats  = (float*)carve(4 * 64 * 64 * 4);    // [layer][64 reps][64]
    size_t zero_bytes = off;                     // everything above must start at 0
    float*  fin    = (float*)carve(4 * 64 * 4);  // folded stats per layer
    int*    rowptr = (int*)carve((size_t)(NN + 1) * 4);
    int*    fill   = (int*)carve((size_t)NN * 4);
    float*  degf   = (float*)carve((size_t)NN * 4);
    float4* sedge  = (float4*)carve((size_t)NE * 16);
    float2* re2    = (float2*)carve((size_t)NE * 8);
    unsigned short* xh0 = (unsigned short*)carve((size_t)NN * 32 * 2);
    unsigned short* xah = (unsigned short*)carve((size_t)NN * 32 * 2);
    float*  vbuf   = (float*)carve((size_t)NN * 32 * 4);
    float*  xa     = (float*)carve((size_t)NN * 32 * 4);
    float*  xb     = (float*)carve((size_t)NN * 32 * 4);
    float*  tb     = (float*)carve((size_t)NN * 32 * 4);
    float*  abl    = (float*)carve((size_t)4096 * 256 * 4);   // ablation scratch (4 MB)

    hipMemsetAsync(d_ws, 0, zero_bytes, stream);
    k_hist<<<NE / 256, 256, 0, stream>>>(ei, cnt);
    k_scan<<<1, 1024, 0, stream>>>(cnt, rowptr, fill, degf);
    k_scatter<<<NE / 256, 256, 0, stream>>>(ei, attr, degf, fill, sedge, re2);
    k_cvt<<<NN * 32 / 256, 256, 0, stream>>>(x_in, xh0);

    // layer 1: spline + leaky + BN0 (BN emits bf16 for layer-2 gather)
    k_spline<<<NN / 4, 256, 0, stream>>>(x_in, xh0, rowptr, sedge, degf, wsp1, root1, bias1, tb, stats);
    k_red<<<1, 64, 0, stream>>>(stats, fin);
    k_bn_cvt<<<NN * 32 / 256, 256, 0, stream>>>(tb, fin, gam, bet, xa, xah);
    // layer 2: spline + leaky + BN1
    k_spline<<<NN / 4, 256, 0, stream>>>(xa, xah, rowptr, sedge, degf, wsp2, root2, bias2, tb, stats + 4096);
    k_red<<<1, 64, 0, stream>>>(stats + 4096, fin + 64);
    k_bn<<<NN * 32 / 256, 256, 0, stream>>>(tb, fin + 64, gam + 32, bet + 32, xb);

    int nfgrid = (NN + 31) / 32;
    // layer 3: nodeformer1 + leaky + BN2
    k_nf1<<<nfgrid, 256, 0, stream>>>(xb, w1qkv, w1p, gum1, vbuf, kvg1);
    k_nf2<<<nfgrid, 256, 0, stream>>>(xb, w1qkv, w1p, b1rel, w1o, b1o, kvg1, rowptr, re2,
                                      vbuf, 1, tb, stats + 8192);
    k_red<<<1, 64, 0, stream>>>(stats + 8192, fin + 128);
    k_bn<<<NN * 32 / 256, 256, 0, stream>>>(tb, fin + 128, gam + 64, bet + 64, xa);
    // layer 4: nodeformer2 + BN3 (no leaky)
    k_nf1<<<nfgrid, 256, 0, stream>>>(xa, w2qkv, w2p, gum2, vbuf, kvg2);
    k_nf2<<<nfgrid, 256, 0, stream>>>(xa, w2qkv, w2p, b2rel, w2o, b2o, kvg2, rowptr, re2,
                                      vbuf, 0, tb, stats + 12288);
    k_red<<<1, 64, 0, stream>>>(stats + 12288, fin + 192);
    k_bn<<<NN * 32 / 256, 256, 0, stream>>>(tb, fin + 192, gam + 96, bet + 96, outp);

    // ===== ablation dispatches (outputs unused; appended after real pipeline) =====
    k_abl_g<<<NN / 4, 256, 0, stream>>>(xh0, rowptr, sedge, abl);
    k_abl_a<<<NN / 4, 256, 0, stream>>>(xh0, rowptr, sedge, abl);
    k_abl_b<<<NN / 4, 256, 0, stream>>>(x_in, degf, wsp1, root1, bias1, abl);
}

// Round 7
// 1285.111 us; speedup vs baseline: 6.3658x; 6.3658x over previous
//
#include <hip/hip_runtime.h>
#include <hip/hip_bf16.h>

#define NN 50000      // nodes
#define NE 800000     // edges
// C=32 channels, K=64 spline kernels, H=8 heads, DH=4, M=32 features

__device__ __forceinline__ void gAdd(float* p, float v) {
    unsafeAtomicAdd(p, v);   // global_atomic_add_f32, no CAS loop
}
__device__ __forceinline__ unsigned short f2bf(float f) {   // RNE bf16
    unsigned u = __float_as_uint(f);
    u += 0x7FFF + ((u >> 16) & 1);
    return (unsigned short)(u >> 16);
}

// ---------------- K1: histogram of dst ----------------
__global__ void k_hist(const int* __restrict__ ei, int* __restrict__ cnt) {
    int e = blockIdx.x * 256 + threadIdx.x;   // grid exact: 3125*256 = 800000
    atomicAdd(&cnt[ei[NE + e]], 1);
}

// ---------------- K2: exclusive scan (single block, shfl-based) ----------------
__global__ void __launch_bounds__(1024) k_scan(const int* __restrict__ cnt,
                                               int* __restrict__ rowptr,
                                               int* __restrict__ fill,
                                               float* __restrict__ degf) {
    __shared__ int wsum[16];
    int tid = threadIdx.x;
    int wave = tid >> 6, lane = tid & 63;
    int carry = 0;
    for (int base = 0; base < NN; base += 8192) {
        int i0 = base + tid * 8;
        int v[8], pre[8], s = 0;
#pragma unroll
        for (int j = 0; j < 8; j++) {
            int i = i0 + j;
            v[j] = (i < NN) ? cnt[i] : 0;
            pre[j] = s; s += v[j];
        }
        int sc = s;
#pragma unroll
        for (int d = 1; d < 64; d <<= 1) {
            int t = __shfl_up(sc, d);
            if (lane >= d) sc += t;
        }
        if (lane == 63) wsum[wave] = sc;
        __syncthreads();
        int wpre = 0, total = 0;
#pragma unroll
        for (int w = 0; w < 16; w++) {
            int x = wsum[w];
            if (w < wave) wpre += x;
            total += x;
        }
        int excl = carry + wpre + (sc - s);
#pragma unroll
        for (int j = 0; j < 8; j++) {
            int i = i0 + j;
            if (i < NN) {
                int st = excl + pre[j];
                rowptr[i] = st;
                fill[i]   = st;
                degf[i]   = (float)(v[j] > 0 ? v[j] : 1);
                if (i == NN - 1) rowptr[NN] = st + v[j];
            }
        }
        carry += total;
        __syncthreads();
    }
}

// ---------------- K3: scatter edges into CSR order (+rel edge table) ----------------
__global__ void k_scatter(const int* __restrict__ ei, const float* __restrict__ attr,
                          const float* __restrict__ degf,
                          int* __restrict__ fill, float4* __restrict__ sedge,
                          float2* __restrict__ re2) {
    int e = blockIdx.x * 256 + threadIdx.x;
    int src = ei[e], dst = ei[NE + e];
    int pos = atomicAdd(&fill[dst], 1);
    float4 r;
    r.x = __int_as_float(src);
    r.y = attr[e * 3 + 0]; r.z = attr[e * 3 + 1]; r.w = attr[e * 3 + 2];
    sedge[pos] = r;
    re2[pos] = make_float2(__int_as_float(src), rsqrtf(degf[src] * degf[dst]));
}

// ---------------- K3b: fp32 -> bf16 row copy ----------------
__global__ void k_cvt(const float* __restrict__ xin, unsigned short* __restrict__ xh) {
    int i = blockIdx.x * 256 + threadIdx.x;   // grid exact: NN*32/256
    xh[i] = f2bf(xin[i]);
}

// ---------------- K4: fused SplineConv + leaky + BN-stats ----------------
// 4 nodes/block, 256 threads. LDS buf layout: [idx(64)][t(4)][c ^ ((idx&7)<<2)]
// NON-ATOMIC RMW: wave owns node t's rows; lanes hit distinct addresses per edge.
__device__ __forceinline__ void edge_rmw(float* __restrict__ buf,
                                         float ay, float az, float aw, int t,
                                         float xs, int ch, int hi) {
    float p0 = ay * 3.f, p1 = az * 3.f, p2 = aw * 3.f;
    float f0 = fmaxf(fminf(floorf(p0), 2.f), 0.f);
    float f1 = fmaxf(fminf(floorf(p1), 2.f), 0.f);
    float f2 = fmaxf(fminf(floorf(p2), 2.f), 0.f);
    float r0 = p0 - f0, r1 = p1 - f1, r2 = p2 - f2;
    int i0 = (int)f0, i1 = (int)f1, i2 = (int)f2;
    int addr0, addr1, addr2, addr3;
    float b0v, b1v, b2v, b3v;
#pragma unroll
    for (int q = 0; q < 4; q++) {
        int bits = hi * 4 + q;
        int b0 = bits & 1, b1 = (bits >> 1) & 1, b2 = (bits >> 2) & 1;
        float bas = (b0 ? r0 : 1.f - r0) * (b1 ? r1 : 1.f - r1) * (b2 ? r2 : 1.f - r2);
        int idx = (i0 + b0) + 4 * (i1 + b1) + 16 * (i2 + b2);
        int a = ((idx * 4 + t) << 5) + (ch ^ ((idx & 7) << 2));
        if (q == 0) { addr0 = a; b0v = bas * xs; }
        else if (q == 1) { addr1 = a; b1v = bas * xs; }
        else if (q == 2) { addr2 = a; b2v = bas * xs; }
        else { addr3 = a; b3v = bas * xs; }
    }
    // 4 distinct addresses within this edge -> batch reads, then writes
    float v0 = buf[addr0], v1 = buf[addr1], v2 = buf[addr2], v3 = buf[addr3];
    buf[addr0] = v0 + b0v;
    buf[addr1] = v1 + b1v;
    buf[addr2] = v2 + b2v;
    buf[addr3] = v3 + b3v;
}

__global__ void __launch_bounds__(256) k_spline(
        const float* __restrict__ xin, const unsigned short* __restrict__ xh,
        const int* __restrict__ rowptr,
        const float4* __restrict__ sedge, const float* __restrict__ degf,
        const float* __restrict__ wsp, const float* __restrict__ root,
        const float* __restrict__ bias, float* __restrict__ out,
        float* __restrict__ stats) {
    __shared__ __align__(16) float buf[8192];   // 64k * 4t * 32c = 32 KB
    __shared__ __align__(16) float xt[4][32];
    __shared__ __align__(16) float scr[1024];   // [wave*2+hf (8)][d8(8)][t(4)][4]
    __shared__ float scr2[2][64];               // per-wave-pair stat slots (no atomics)
    int tid = threadIdx.x;
    int wave = tid >> 6, lane = tid & 63;
    for (int i = tid; i < 8192; i += 256) buf[i] = 0.f;
    int nb = blockIdx.x * 4;                    // NN % 4 == 0
    if (tid < 128) {
        int t = tid >> 5, c = tid & 31;
        xt[t][c] = xin[(nb + t) * 32 + c];
    }
    __syncthreads();
    // -------- phase A: wave w owns node nb+w; coalesced edge sweep + shfl + 8-deep gather --------
    {
        int n = nb + wave;
        int rs = rowptr[n], re = rowptr[n + 1];
        int ch = lane & 31, hi = lane >> 5;
        for (int ce = rs; ce < re; ce += 64) {
            int cnt = re - ce; if (cnt > 64) cnt = 64;
            float4 myed = make_float4(0.f, 0.f, 0.f, 0.f);
            if (lane < cnt) myed = sedge[ce + lane];
            int mysrc = __float_as_int(myed.x);
            for (int j0 = 0; j0 < cnt; j0 += 8) {
                float xsv[8], ey[8], ez[8], ew[8];
#pragma unroll
                for (int jj = 0; jj < 8; jj++) {
                    int j = j0 + jj;
                    int s  = __shfl(mysrc, j);
                    ey[jj] = __shfl(myed.y, j);
                    ez[jj] = __shfl(myed.z, j);
                    ew[jj] = __shfl(myed.w, j);
                    int sc = (j < cnt) ? s : 0;
                    unsigned short u = xh[sc * 32 + ch];   // bf16 row gather (64B line)
                    xsv[jj] = __uint_as_float(((unsigned)u) << 16);
                }
#pragma unroll
                for (int jj = 0; jj < 8; jj++) {
                    int j = j0 + jj;
                    if (j < cnt)
                        edge_rmw(buf, ey[jj], ez[jj], ew[jj], wave, xsv[jj], ch, hi);
                }
            }
        }
    }
    __syncthreads();
    // -------- phase B: einsum nkc,kcd -> nd ; k = hf*32 + wave*8 + kk --------
    int kk = lane >> 3, d8 = lane & 7;
    float4 acc[2][4];
#pragma unroll
    for (int hf = 0; hf < 2; hf++)
#pragma unroll
        for (int t = 0; t < 4; t++) acc[hf][t] = make_float4(0.f, 0.f, 0.f, 0.f);
#pragma unroll
    for (int hf = 0; hf < 2; hf++) {
        int k = hf * 32 + wave * 8 + kk;        // k&7 == kk
        const float* wk = wsp + k * 1024;
#pragma unroll
        for (int c4 = 0; c4 < 8; c4++) {
            float4 wv0 = *(const float4*)(wk + (c4 * 4 + 0) * 32 + d8 * 4);
            float4 wv1 = *(const float4*)(wk + (c4 * 4 + 1) * 32 + d8 * 4);
            float4 wv2 = *(const float4*)(wk + (c4 * 4 + 2) * 32 + d8 * 4);
            float4 wv3 = *(const float4*)(wk + (c4 * 4 + 3) * 32 + d8 * 4);
            int cp = (c4 ^ kk) << 2;
            const float* bp = &buf[(k * 4) << 5];
#pragma unroll
            for (int t = 0; t < 4; t++) {
                float4 bv = *(const float4*)(bp + (t << 5) + cp);
                acc[hf][t].x += bv.x * wv0.x + bv.y * wv1.x + bv.z * wv2.x + bv.w * wv3.x;
                acc[hf][t].y += bv.x * wv0.y + bv.y * wv1.y + bv.z * wv2.y + bv.w * wv3.y;
                acc[hf][t].z += bv.x * wv0.z + bv.y * wv1.z + bv.z * wv2.z + bv.w * wv3.z;
                acc[hf][t].w += bv.x * wv0.w + bv.y * wv1.w + bv.z * wv2.w + bv.w * wv3.w;
            }
        }
    }
#pragma unroll
    for (int hf = 0; hf < 2; hf++)
#pragma unroll
    for (int t = 0; t < 4; t++) {
        float sx = acc[hf][t].x, sy = acc[hf][t].y, sz = acc[hf][t].z, sw = acc[hf][t].w;
        sx += __shfl_xor(sx, 8);  sy += __shfl_xor(sy, 8);  sz += __shfl_xor(sz, 8);  sw += __shfl_xor(sw, 8);
        sx += __shfl_xor(sx, 16); sy += __shfl_xor(sy, 16); sz += __shfl_xor(sz, 16); sw += __shfl_xor(sw, 16);
        sx += __shfl_xor(sx, 32); sy += __shfl_xor(sy, 32); sz += __shfl_xor(sz, 32); sw += __shfl_xor(sw, 32);
        acc[hf][t] = make_float4(sx, sy, sz, sw);
    }
    if (kk == 0) {
#pragma unroll
        for (int hf = 0; hf < 2; hf++)
#pragma unroll
        for (int t = 0; t < 4; t++)
            *(float4*)&scr[(wave * 2 + hf) * 128 + d8 * 16 + t * 4] = acc[hf][t];
    }
    __syncthreads();
    if (tid < 128) {
        int t = tid >> 5, d = tid & 31;
        int n = nb + t;
        float v = 0.f;
#pragma unroll
        for (int wh = 0; wh < 8; wh++)
            v += scr[wh * 128 + (d >> 2) * 16 + t * 4 + (d & 3)];
        v /= degf[n];
        float rt = 0.f;
#pragma unroll
        for (int c = 0; c < 32; c++) rt += xt[t][c] * root[c * 32 + d];
        v += rt + bias[d];
        v = v >= 0.f ? v : 0.01f * v;   // LeakyReLU (both spline layers)
        out[n * 32 + d] = v;
        float s = v, s2 = v * v;
        s += __shfl_xor(s, 32); s2 += __shfl_xor(s2, 32);
        if ((tid & 63) < 32) {          // lanes 0-31 of waves 0,1: plain per-wave slots
            scr2[tid >> 6][d] = s;
            scr2[tid >> 6][32 + d] = s2;
        }
    }
    __syncthreads();
    // replicated stats: spreads atomics over 64 slots (no hot lines)
    if (tid < 64) gAdd(&stats[(blockIdx.x & 63) * 64 + tid], scr2[0][tid] + scr2[1][tid]);
}

// ---------------- K4b: fold 64 replicated stat slots ----------------
__global__ void k_red(const float* __restrict__ stats, float* __restrict__ fin) {
    int j = threadIdx.x;   // 64 threads
    float s = 0.f;
#pragma unroll 8
    for (int r = 0; r < 64; r++) s += stats[r * 64 + j];
    fin[j] = s;
}

// ---------------- K5: BN apply (optionally also emit bf16 copy) ----------------
__global__ void k_bn(const float* __restrict__ tin, const float* __restrict__ fin,
                     const float* __restrict__ gamma, const float* __restrict__ beta,
                     float* __restrict__ xout) {
    int i = blockIdx.x * 256 + threadIdx.x;   // grid exact
    int c = i & 31;
    float mu = fin[c] * (1.f / NN);
    float var = fin[32 + c] * (1.f / NN) - mu * mu;
    float g = gamma[c] * rsqrtf(var + 1e-5f);
    xout[i] = (tin[i] - mu) * g + beta[c];
}
__global__ void k_bn_cvt(const float* __restrict__ tin, const float* __restrict__ fin,
                         const float* __restrict__ gamma, const float* __restrict__ beta,
                         float* __restrict__ xout, unsigned short* __restrict__ xh) {
    int i = blockIdx.x * 256 + threadIdx.x;
    int c = i & 31;
    float mu = fin[c] * (1.f / NN);
    float var = fin[32 + c] * (1.f / NN) - mu * mu;
    float g = gamma[c] * rsqrtf(var + 1e-5f);
    float v = (tin[i] - mu) * g + beta[c];
    xout[i] = v;
    xh[i] = f2bf(v);
}

// ---------------- K6a: NodeFormer pass 1 (two-stage, NO LDS atomics) ----------------
// stage 1: threads (nl=tid>>3, h=tid&7) compute k,v; stash scaled-k, v, sq, gs in LDS.
// stage 2: threads (h2=tid>>5, m=tid&31) own register accumulators, loop the 32 nodes.
__global__ void __launch_bounds__(256) k_nf1(
        const float* __restrict__ x, const float* __restrict__ wqkv,
        const float* __restrict__ wp, const float* __restrict__ gumbel,
        float* __restrict__ vbuf, float* __restrict__ kvg) {
    __shared__ float xl[32 * 33];
    __shared__ __align__(16) float kq[32][8][4];
    __shared__ __align__(16) float vv[32][8][4];
    __shared__ float sqv[32][8];
    __shared__ float gsv[32][8];
    int tid = threadIdx.x;
    int base = blockIdx.x * 32;
#pragma unroll
    for (int r = 0; r < 4; r++) {
        int i = r * 256 + tid;
        int gi = base * 32 + i;
        float v = (gi < NN * 32) ? x[gi] : 0.f;
        xl[(i >> 5) * 33 + (i & 31)] = v;
    }
    __syncthreads();
    int nl = tid >> 3, h = tid & 7;
    int n = base + nl;
    int act = (n < NN) ? 1 : 0;
    const float* xp = &xl[nl * 33];
    float kr0 = 0, kr1 = 0, kr2 = 0, kr3 = 0, vr0 = 0, vr1 = 0, vr2 = 0, vr3 = 0;
#pragma unroll
    for (int c = 0; c < 32; c++) {
        float xc = xp[c];
        const float4 wk4 = *(const float4*)(wqkv + 1024 + c * 32 + h * 4);
        const float4 wv4 = *(const float4*)(wqkv + 2048 + c * 32 + h * 4);
        kr0 += xc * wk4.x; kr1 += xc * wk4.y; kr2 += xc * wk4.z; kr3 += xc * wk4.w;
        vr0 += xc * wv4.x; vr1 += xc * wv4.y; vr2 += xc * wv4.z; vr3 += xc * wv4.w;
    }
    if (act) *(float4*)&vbuf[n * 32 + h * 4] = make_float4(vr0, vr1, vr2, vr3);
    const float inv_rt2 = 0.70710678118f;     // 1/DH^0.25
    const float invSqM = 0.17677669529f;      // 1/sqrt(32)
    float x0 = kr0 * inv_rt2, x1 = kr1 * inv_rt2, x2 = kr2 * inv_rt2, x3 = kr3 * inv_rt2;
    float sq = 0.5f * (x0 * x0 + x1 * x1 + x2 * x2 + x3 * x3);
    float gs = act ? (__expf(gumbel[(act ? n : 0) * 8 + h]) * invSqM) : 0.f;
    *(float4*)&kq[nl][h][0] = make_float4(x0, x1, x2, x3);
    *(float4*)&vv[nl][h][0] = make_float4(vr0, vr1, vr2, vr3);
    sqv[nl][h] = sq;
    gsv[nl][h] = gs;
    __syncthreads();
    // stage 2: register accumulation over the block's 32 nodes
    int h2 = tid >> 5, m = tid & 31;
    const float* wph = wp + h2 * 128;
    float w0 = wph[m], w1 = wph[32 + m], w2 = wph[64 + m], w3 = wph[96 + m];
    float ks = 0.f, a0 = 0.f, a1 = 0.f, a2 = 0.f, a3 = 0.f;
#pragma unroll 4
    for (int nn2 = 0; nn2 < 32; nn2++) {
        float4 k4 = *(const float4*)&kq[nn2][h2][0];
        float4 v4 = *(const float4*)&vv[nn2][h2][0];
        float pr = k4.x * w0 + k4.y * w1 + k4.z * w2 + k4.w * w3;
        float phk = __expf(pr - sqv[nn2][h2]) * gsv[nn2][h2];
        ks += phk;
        a0 += phk * v4.x; a1 += phk * v4.y; a2 += phk * v4.z; a3 += phk * v4.w;
    }
    // replicated kvg: 8 slots; layout [dh(4)][h(8)][m(32)], ksum at 1024+
    float* kvr = kvg + (blockIdx.x & 7) * 1280;
    gAdd(&kvr[1024 + h2 * 32 + m], ks);
    gAdd(&kvr[0 * 256 + h2 * 32 + m], a0);
    gAdd(&kvr[1 * 256 + h2 * 32 + m], a1);
    gAdd(&kvr[2 * 256 + h2 * 32 + m], a2);
    gAdd(&kvr[3 * 256 + h2 * 32 + m], a3);
}

// ---------------- K6b: NodeFormer pass 2 ----------------
__global__ void __launch_bounds__(256) k_nf2(
        const float* __restrict__ x, const float* __restrict__ wqkv,
        const float* __restrict__ wp, const float* __restrict__ brel,
        const float* __restrict__ wo, const float* __restrict__ bo,
        const float* __restrict__ kvg, const int* __restrict__ rowptr,
        const float2* __restrict__ re2, const float* __restrict__ vbuf,
        int do_leaky, float* __restrict__ out, float* __restrict__ stats) {
    __shared__ float xl[32 * 33];
    __shared__ float ylds[32 * 33];
    __shared__ float kvs[1280];
    __shared__ float scr2[4][64];    // per-wave stat slots (no atomics)
    int tid = threadIdx.x;
    int base = blockIdx.x * 32;
#pragma unroll
    for (int r = 0; r < 4; r++) {
        int i = r * 256 + tid;
        int gi = base * 32 + i;
        float v = (gi < NN * 32) ? x[gi] : 0.f;
        xl[(i >> 5) * 33 + (i & 31)] = v;
    }
    // stage kv summary: sum the 8 replicated slots into LDS
    for (int i = tid; i < 1280; i += 256) {
        float s = 0.f;
#pragma unroll
        for (int r = 0; r < 8; r++) s += kvg[r * 1280 + i];
        kvs[i] = s;
    }
    __syncthreads();
    int nl = tid >> 3, h = tid & 7;
    int n = base + nl;
    int act = (n < NN) ? 1 : 0;
    int nc = act ? n : (NN - 1);
    const float* xp = &xl[nl * 33];
    float q0 = 0, q1 = 0, q2 = 0, q3 = 0;
#pragma unroll
    for (int c = 0; c < 32; c++) {
        float xc = xp[c];
        const float4 wq4 = *(const float4*)(wqkv + c * 32 + h * 4);
        q0 += xc * wq4.x; q1 += xc * wq4.y; q2 += xc * wq4.z; q3 += xc * wq4.w;
    }
    const float inv_rt2 = 0.70710678118f;
    const float invSqM = 0.17677669529f;
    float x0 = q0 * inv_rt2, x1 = q1 * inv_rt2, x2 = q2 * inv_rt2, x3 = q3 * inv_rt2;
    float sq = 0.5f * (x0 * x0 + x1 * x1 + x2 * x2 + x3 * x3);
    const float* wph = wp + h * 128;
    float den = 0.f, n0 = 0.f, n1 = 0.f, n2 = 0.f, n3 = 0.f;
    for (int mm = 0; mm < 32; mm++) {
        int m = (mm + 4 * h) & 31;            // h-stagger: LDS bank-clean
        float pr = x0 * wph[m] + x1 * wph[32 + m] + x2 * wph[64 + m] + x3 * wph[96 + m];
        float phq = __expf(pr - sq) * invSqM;
        den += phq * kvs[1024 + h * 32 + m];
        n0 += phq * kvs[0 * 256 + h * 32 + m];
        n1 += phq * kvs[1 * 256 + h * 32 + m];
        n2 += phq * kvs[2 * 256 + h * 32 + m];
        n3 += phq * kvs[3 * 256 + h * 32 + m];
    }
    float inv = 1.f / (den + 1e-6f);
    float y0 = n0 * inv, y1 = n1 * inv, y2 = n2 * inv, y3 = n3 * inv;
    // relational bias: 8-deep shfl-batched vbuf row gathers
    float r0 = 0, r1 = 0, r2 = 0, r3 = 0;
    int rs = rowptr[nc];
    int re = act ? rowptr[nc + 1] : rs;
    int lb = (tid & 63) & 56;                 // wave-lane base of this node's 8-group
    for (int e0 = rs; e0 < re; e0 += 8) {
        int cnt = re - e0; if (cnt > 8) cnt = 8;
        float2 med = make_float2(__int_as_float(0), 0.f);
        if (h < cnt) med = re2[e0 + h];
        int msrc = __float_as_int(med.x);
        float4 xs4[8];
        float nrj[8];
#pragma unroll
        for (int jj = 0; jj < 8; jj++) {
            int s   = __shfl(msrc, lb + jj);
            float nr = __shfl(med.y, lb + jj);
            nrj[jj] = (jj < cnt) ? nr : 0.f;
            int sc  = (jj < cnt) ? s : 0;
            xs4[jj] = *(const float4*)&vbuf[sc * 32 + h * 4];
        }
#pragma unroll
        for (int jj = 0; jj < 8; jj++) {
            r0 += nrj[jj] * xs4[jj].x;
            r1 += nrj[jj] * xs4[jj].y;
            r2 += nrj[jj] * xs4[jj].z;
            r3 += nrj[jj] * xs4[jj].w;
        }
    }
    float sg = 1.f / (1.f + __expf(-brel[h]));
    y0 += sg * r0; y1 += sg * r1; y2 += sg * r2; y3 += sg * r3;
    ylds[nl * 33 + h * 4 + 0] = y0;
    ylds[nl * 33 + h * 4 + 1] = y1;
    ylds[nl * 33 + h * 4 + 2] = y2;
    ylds[nl * 33 + h * 4 + 3] = y3;
    __syncthreads();
    // output projection: thread (nl,h) computes z[d = h*4 .. h*4+3]
    const float* yp = &ylds[nl * 33];
    const float4 b4 = *(const float4*)(bo + h * 4);
    float z0 = b4.x, z1 = b4.y, z2 = b4.z, z3 = b4.w;
#pragma unroll
    for (int j = 0; j < 32; j++) {
        float yv = yp[j];
        const float4 w4 = *(const float4*)(wo + j * 32 + h * 4);
        z0 += yv * w4.x; z1 += yv * w4.y; z2 += yv * w4.z; z3 += yv * w4.w;
    }
    if (do_leaky) {
        z0 = z0 >= 0.f ? z0 : 0.01f * z0;
        z1 = z1 >= 0.f ? z1 : 0.01f * z1;
        z2 = z2 >= 0.f ? z2 : 0.01f * z2;
        z3 = z3 >= 0.f ? z3 : 0.01f * z3;
    }
    if (act) *(float4*)&out[n * 32 + h * 4] = make_float4(z0, z1, z2, z3);
    // BN stats: shfl-reduce over nl within wave; lanes 0-7 store to per-wave slots
    int wv = tid >> 6;
    float sv[4] = {act ? z0 : 0.f, act ? z1 : 0.f, act ? z2 : 0.f, act ? z3 : 0.f};
#pragma unroll
    for (int j = 0; j < 4; j++) {
        float s = sv[j], s2 = sv[j] * sv[j];
        s += __shfl_xor(s, 8);  s2 += __shfl_xor(s2, 8);
        s += __shfl_xor(s, 16); s2 += __shfl_xor(s2, 16);
        s += __shfl_xor(s, 32); s2 += __shfl_xor(s2, 32);
        if (((tid & 63) >> 3) == 0) {     // lanes 0-7: h == lane
            scr2[wv][h * 4 + j] = s;
            scr2[wv][32 + h * 4 + j] = s2;
        }
    }
    __syncthreads();
    if (tid < 64)
        gAdd(&stats[(blockIdx.x & 63) * 64 + tid],
             scr2[0][tid] + scr2[1][tid] + scr2[2][tid] + scr2[3][tid]);
}

extern "C" void kernel_launch(void* const* d_in, const int* in_sizes, int n_in,
                              void* d_out, int out_size, void* d_ws, size_t ws_size,
                              hipStream_t stream) {
    (void)in_sizes; (void)n_in; (void)out_size; (void)ws_size;
    const float* x_in  = (const float*)d_in[0];
    const int*   ei    = (const int*)d_in[1];
    const float* attr  = (const float*)d_in[2];
    const float* wsp1  = (const float*)d_in[3];
    const float* root1 = (const float*)d_in[4];
    const float* bias1 = (const float*)d_in[5];
    const float* wsp2  = (const float*)d_in[6];
    const float* root2 = (const float*)d_in[7];
    const float* bias2 = (const float*)d_in[8];
    const float* gam   = (const float*)d_in[9];
    const float* bet   = (const float*)d_in[10];
    const float* w1qkv = (const float*)d_in[11];
    const float* w1p   = (const float*)d_in[12];
    const float* b1rel = (const float*)d_in[13];
    const float* w1o   = (const float*)d_in[14];
    const float* b1o   = (const float*)d_in[15];
    const float* gum1  = (const float*)d_in[16];
    const float* w2qkv = (const float*)d_in[17];
    const float* w2p   = (const float*)d_in[18];
    const float* b2rel = (const float*)d_in[19];
    const float* w2o   = (const float*)d_in[20];
    const float* b2o   = (const float*)d_in[21];
    const float* gum2  = (const float*)d_in[22];
    float* outp = (float*)d_out;

    char* wsb = (char*)d_ws;
    size_t off = 0;
    auto carve = [&](size_t bytes) -> char* {
        char* p = wsb + off;
        off += (bytes + 255) & ~(size_t)255;
        return p;
    };
    int*    cnt    = (int*)carve((size_t)NN * 4);
    float*  kvg1   = (float*)carve(8 * 1280 * 4);
    float*  kvg2   = (float*)carve(8 * 1280 * 4);
    float*  stats  = (float*)carve(4 * 64 * 64 * 4);    // [layer][64 reps][64]
    size_t zero_bytes = off;                     // everything above must start at 0
    float*  fin    = (float*)carve(4 * 64 * 4);  // folded stats per layer
    int*    rowptr = (int*)carve((size_t)(NN + 1) * 4);
    int*    fill   = (int*)carve((size_t)NN * 4);
    float*  degf   = (float*)carve((size_t)NN * 4);
    float4* sedge  = (float4*)carve((size_t)NE * 16);
    float2* re2    = (float2*)carve((size_t)NE * 8);
    unsigned short* xh0 = (unsigned short*)carve((size_t)NN * 32 * 2);
    unsigned short* xah = (unsigned short*)carve((size_t)NN * 32 * 2);
    float*  vbuf   = (float*)carve((size_t)NN * 32 * 4);
    float*  xa     = (float*)carve((size_t)NN * 32 * 4);
    float*  xb     = (float*)carve((size_t)NN * 32 * 4);
    float*  tb     = (float*)carve((size_t)NN * 32 * 4);

    hipMemsetAsync(d_ws, 0, zero_bytes, stream);
    k_hist<<<NE / 256, 256, 0, stream>>>(ei, cnt);
    k_scan<<<1, 1024, 0, stream>>>(cnt, rowptr, fill, degf);
    k_scatter<<<NE / 256, 256, 0, stream>>>(ei, attr, degf, fill, sedge, re2);
    k_cvt<<<NN * 32 / 256, 256, 0, stream>>>(x_in, xh0);

    // layer 1: spline + leaky + BN0 (BN emits bf16 for layer-2 gather)
    k_spline<<<NN / 4, 256, 0, stream>>>(x_in, xh0, rowptr, sedge, degf, wsp1, root1, bias1, tb, stats);
    k_red<<<1, 64, 0, stream>>>(stats, fin);
    k_bn_cvt<<<NN * 32 / 256, 256, 0, stream>>>(tb, fin, gam, bet, xa, xah);
    // layer 2: spline + leaky + BN1
    k_spline<<<NN / 4, 256, 0, stream>>>(xa, xah, rowptr, sedge, degf, wsp2, root2, bias2, tb, stats + 4096);
    k_red<<<1, 64, 0, stream>>>(stats + 4096, fin + 64);
    k_bn<<<NN * 32 / 256, 256, 0, stream>>>(tb, fin + 64, gam + 32, bet + 32, xb);

    int nfgrid = (NN + 31) / 32;
    // layer 3: nodeformer1 + leaky + BN2
    k_nf1<<<nfgrid, 256, 0, stream>>>(xb, w1qkv, w1p, gum1, vbuf, kvg1);
    k_nf2<<<nfgrid, 256, 0, stream>>>(xb, w1qkv, w1p, b1rel, w1o, b1o, kvg1, rowptr, re2,
                                      vbuf, 1, tb, stats + 8192);
    k_red<<<1, 64, 0, stream>>>(stats + 8192, fin + 128);
    k_bn<<<NN * 32 / 256, 256, 0, stream>>>(tb, fin + 128, gam + 64, bet + 64, xa);
    // layer 4: nodeformer2 + BN3 (no leaky)
    k_nf1<<<nfgrid, 256, 0, stream>>>(xa, w2qkv, w2p, gum2, vbuf, kvg2);
    k_nf2<<<nfgrid, 256, 0, stream>>>(xa, w2qkv, w2p, b2rel, w2o, b2o, kvg2, rowptr, re2,
                                      vbuf, 0, tb, stats + 12288);
    k_red<<<1, 64, 0, stream>>>(stats + 12288, fin + 192);
    k_bn<<<NN * 32 / 256, 256, 0, stream>>>(tb, fin + 192, gam + 96, bet + 96, outp);
}

// Round 8
// 1250.280 us; speedup vs baseline: 6.5431x; 1.0279x over previous
//
#include <hip/hip_runtime.h>
#include <hip/hip_bf16.h>
#include <hip/hip_fp16.h>

#define NN 50000      // nodes
#define NE 800000     // edges
// C=32 channels, K=64 spline kernels, H=8 heads, DH=4, M=32 features

__device__ __forceinline__ void gAdd(float* p, float v) {
    unsafeAtomicAdd(p, v);   // global_atomic_add_f32, no CAS loop
}
__device__ __forceinline__ unsigned short f2bf(float f) {   // RNE bf16
    unsigned u = __float_as_uint(f);
    u += 0x7FFF + ((u >> 16) & 1);
    return (unsigned short)(u >> 16);
}

// ---------------- K1: histogram of dst ----------------
__global__ void k_hist(const int* __restrict__ ei, int* __restrict__ cnt) {
    int e = blockIdx.x * 256 + threadIdx.x;   // grid exact: 3125*256 = 800000
    atomicAdd(&cnt[ei[NE + e]], 1);
}

// ---------------- K2: exclusive scan (single block, shfl-based) ----------------
__global__ void __launch_bounds__(1024) k_scan(const int* __restrict__ cnt,
                                               int* __restrict__ rowptr,
                                               int* __restrict__ fill,
                                               float* __restrict__ degf) {
    __shared__ int wsum[16];
    int tid = threadIdx.x;
    int wave = tid >> 6, lane = tid & 63;
    int carry = 0;
    for (int base = 0; base < NN; base += 8192) {
        int i0 = base + tid * 8;
        int v[8], pre[8], s = 0;
#pragma unroll
        for (int j = 0; j < 8; j++) {
            int i = i0 + j;
            v[j] = (i < NN) ? cnt[i] : 0;
            pre[j] = s; s += v[j];
        }
        int sc = s;
#pragma unroll
        for (int d = 1; d < 64; d <<= 1) {
            int t = __shfl_up(sc, d);
            if (lane >= d) sc += t;
        }
        if (lane == 63) wsum[wave] = sc;
        __syncthreads();
        int wpre = 0, total = 0;
#pragma unroll
        for (int w = 0; w < 16; w++) {
            int x = wsum[w];
            if (w < wave) wpre += x;
            total += x;
        }
        int excl = carry + wpre + (sc - s);
#pragma unroll
        for (int j = 0; j < 8; j++) {
            int i = i0 + j;
            if (i < NN) {
                int st = excl + pre[j];
                rowptr[i] = st;
                fill[i]   = st;
                degf[i]   = (float)(v[j] > 0 ? v[j] : 1);
                if (i == NN - 1) rowptr[NN] = st + v[j];
            }
        }
        carry += total;
        __syncthreads();
    }
}

// ---------------- K3: scatter edges into CSR order, precompute basis ----------------
// record (8 ints = 32B): [0]=src [1]=idxbase [2..5]= 8 x fp16 basis (pairs)
__global__ void k_scatter(const int* __restrict__ ei, const float* __restrict__ attr,
                          const float* __restrict__ degf,
                          int* __restrict__ fill, int* __restrict__ sedgeP,
                          float2* __restrict__ re2) {
    int e = blockIdx.x * 256 + threadIdx.x;
    int src = ei[e], dst = ei[NE + e];
    int pos = atomicAdd(&fill[dst], 1);
    float p0 = attr[e * 3 + 0] * 3.f, p1 = attr[e * 3 + 1] * 3.f, p2 = attr[e * 3 + 2] * 3.f;
    float f0 = fmaxf(fminf(floorf(p0), 2.f), 0.f);
    float f1 = fmaxf(fminf(floorf(p1), 2.f), 0.f);
    float f2 = fmaxf(fminf(floorf(p2), 2.f), 0.f);
    float r0 = p0 - f0, r1 = p1 - f1, r2 = p2 - f2;
    int idxb = (int)f0 + 4 * (int)f1 + 16 * (int)f2;
    unsigned hw[8];
#pragma unroll
    for (int bits = 0; bits < 8; bits++) {
        int b0 = bits & 1, b1 = (bits >> 1) & 1, b2 = (bits >> 2) & 1;
        float bas = (b0 ? r0 : 1.f - r0) * (b1 ? r1 : 1.f - r1) * (b2 ? r2 : 1.f - r2);
        hw[bits] = (unsigned)__half_as_ushort(__float2half(bas));
    }
    int b = pos * 8;
    sedgeP[b + 0] = src;
    sedgeP[b + 1] = idxb;
    sedgeP[b + 2] = (int)(hw[0] | (hw[1] << 16));
    sedgeP[b + 3] = (int)(hw[2] | (hw[3] << 16));
    sedgeP[b + 4] = (int)(hw[4] | (hw[5] << 16));
    sedgeP[b + 5] = (int)(hw[6] | (hw[7] << 16));
    re2[pos] = make_float2(__int_as_float(src), rsqrtf(degf[src] * degf[dst]));
}

// ---------------- K3b: fp32 -> bf16 row copy ----------------
__global__ void k_cvt(const float* __restrict__ xin, unsigned short* __restrict__ xh) {
    int i = blockIdx.x * 256 + threadIdx.x;   // grid exact: NN*32/256
    xh[i] = f2bf(xin[i]);
}

// ---------------- K4: fused SplineConv + leaky + BN-stats ----------------
// 4 nodes/block, 256 threads. LDS buf layout: [idx(64)][t(4)][c ^ ((idx&7)<<2)]
__global__ void __launch_bounds__(256) k_spline(
        const float* __restrict__ xin, const unsigned short* __restrict__ xh,
        const int* __restrict__ rowptr,
        const int* __restrict__ sedgeP, const float* __restrict__ degf,
        const float* __restrict__ wsp, const float* __restrict__ root,
        const float* __restrict__ bias, float* __restrict__ out,
        float* __restrict__ stats) {
    __shared__ __align__(16) float buf[8192];   // 64k * 4t * 32c = 32 KB
    __shared__ __align__(16) float xt[4][32];
    __shared__ __align__(16) float scr[1024];   // [wave*2+hf (8)][d8(8)][t(4)][4]
    __shared__ float scr2[2][64];               // per-wave-pair stat slots (no atomics)
    int tid = threadIdx.x;
    int wave = tid >> 6, lane = tid & 63;
    for (int i = tid; i < 8192; i += 256) buf[i] = 0.f;
    int nb = blockIdx.x * 4;                    // NN % 4 == 0
    if (tid < 128) {
        int t = tid >> 5, c = tid & 31;
        xt[t][c] = xin[(nb + t) * 32 + c];
    }
    __syncthreads();
    // -------- phase A: wave owns node nb+wave; precomputed basis records --------
    {
        int n = nb + wave;
        int rs = rowptr[n], re = rowptr[n + 1];
        int ch = lane & 31, hi = lane >> 5;
        int tof = wave << 5;                    // t*32 component of addr
        for (int ce = rs; ce < re; ce += 64) {
            int cnt = re - ce; if (cnt > 64) cnt = 64;
            int2 hdr = make_int2(0, 0);
            if (lane < cnt) hdr = *(const int2*)&sedgeP[(ce + lane) * 8];  // warms lines
            int mysrc = hdr.x, myidxb = hdr.y;
            for (int j0 = 0; j0 < cnt; j0 += 8) {
                float xsv[8]; int ib2[8]; uint2 wp[8];
#pragma unroll
                for (int jj = 0; jj < 8; jj++) {
                    int j = j0 + jj;
                    int s  = __shfl(mysrc, j);
                    int ib = __shfl(myidxb, j);
                    int ok = (j < cnt);
                    int sc = ok ? s : 0;
                    int je = ce + (ok ? j : 0);
                    unsigned short u = xh[sc * 32 + ch];   // bf16 row gather (64B line)
                    xsv[jj] = __uint_as_float(((unsigned)u) << 16);
                    ib2[jj] = ib + (hi << 4);
                    wp[jj]  = *(const uint2*)&sedgeP[je * 8 + 2 + hi * 2];  // L1 hit
                }
#pragma unroll
                for (int jj = 0; jj < 8; jj++) {
                    int j = j0 + jj;
                    if (j < cnt) {
                        uint2 w = wp[jj];
                        float xs = xsv[jj];
                        float b0 = __half2float(__ushort_as_half((unsigned short)(w.x & 0xFFFF)));
                        float b1 = __half2float(__ushort_as_half((unsigned short)(w.x >> 16)));
                        float b2 = __half2float(__ushort_as_half((unsigned short)(w.y & 0xFFFF)));
                        float b3 = __half2float(__ushort_as_half((unsigned short)(w.y >> 16)));
                        int i0 = ib2[jj], i1 = i0 + 1, i2 = i0 + 4, i3 = i0 + 5;
                        int a0 = (i0 << 7) + tof + (ch ^ ((i0 & 7) << 2));
                        int a1 = (i1 << 7) + tof + (ch ^ ((i1 & 7) << 2));
                        int a2 = (i2 << 7) + tof + (ch ^ ((i2 & 7) << 2));
                        int a3 = (i3 << 7) + tof + (ch ^ ((i3 & 7) << 2));
                        float v0 = buf[a0], v1 = buf[a1], v2 = buf[a2], v3 = buf[a3];
                        buf[a0] = v0 + b0 * xs;
                        buf[a1] = v1 + b1 * xs;
                        buf[a2] = v2 + b2 * xs;
                        buf[a3] = v3 + b3 * xs;
                    }
                }
            }
        }
    }
    __syncthreads();
    // -------- phase B: einsum nkc,kcd -> nd ; k = hf*32 + wave*8 + kk --------
    int kk = lane >> 3, d8 = lane & 7;
    float4 acc[2][4];
#pragma unroll
    for (int hf = 0; hf < 2; hf++)
#pragma unroll
        for (int t = 0; t < 4; t++) acc[hf][t] = make_float4(0.f, 0.f, 0.f, 0.f);
#pragma unroll
    for (int hf = 0; hf < 2; hf++) {
        int k = hf * 32 + wave * 8 + kk;        // k&7 == kk
        const float* wk = wsp + k * 1024;
#pragma unroll
        for (int c4 = 0; c4 < 8; c4++) {
            float4 wv0 = *(const float4*)(wk + (c4 * 4 + 0) * 32 + d8 * 4);
            float4 wv1 = *(const float4*)(wk + (c4 * 4 + 1) * 32 + d8 * 4);
            float4 wv2 = *(const float4*)(wk + (c4 * 4 + 2) * 32 + d8 * 4);
            float4 wv3 = *(const float4*)(wk + (c4 * 4 + 3) * 32 + d8 * 4);
            int cp = (c4 ^ kk) << 2;
            const float* bp = &buf[(k * 4) << 5];
#pragma unroll
            for (int t = 0; t < 4; t++) {
                float4 bv = *(const float4*)(bp + (t << 5) + cp);
                acc[hf][t].x += bv.x * wv0.x + bv.y * wv1.x + bv.z * wv2.x + bv.w * wv3.x;
                acc[hf][t].y += bv.x * wv0.y + bv.y * wv1.y + bv.z * wv2.y + bv.w * wv3.y;
                acc[hf][t].z += bv.x * wv0.z + bv.y * wv1.z + bv.z * wv2.z + bv.w * wv3.z;
                acc[hf][t].w += bv.x * wv0.w + bv.y * wv1.w + bv.z * wv2.w + bv.w * wv3.w;
            }
        }
    }
#pragma unroll
    for (int hf = 0; hf < 2; hf++)
#pragma unroll
    for (int t = 0; t < 4; t++) {
        float sx = acc[hf][t].x, sy = acc[hf][t].y, sz = acc[hf][t].z, sw = acc[hf][t].w;
        sx += __shfl_xor(sx, 8);  sy += __shfl_xor(sy, 8);  sz += __shfl_xor(sz, 8);  sw += __shfl_xor(sw, 8);
        sx += __shfl_xor(sx, 16); sy += __shfl_xor(sy, 16); sz += __shfl_xor(sz, 16); sw += __shfl_xor(sw, 16);
        sx += __shfl_xor(sx, 32); sy += __shfl_xor(sy, 32); sz += __shfl_xor(sz, 32); sw += __shfl_xor(sw, 32);
        acc[hf][t] = make_float4(sx, sy, sz, sw);
    }
    if (kk == 0) {
#pragma unroll
        for (int hf = 0; hf < 2; hf++)
#pragma unroll
        for (int t = 0; t < 4; t++)
            *(float4*)&scr[(wave * 2 + hf) * 128 + d8 * 16 + t * 4] = acc[hf][t];
    }
    __syncthreads();
    if (tid < 128) {
        int t = tid >> 5, d = tid & 31;
        int n = nb + t;
        float v = 0.f;
#pragma unroll
        for (int wh = 0; wh < 8; wh++)
            v += scr[wh * 128 + (d >> 2) * 16 + t * 4 + (d & 3)];
        v /= degf[n];
        float rt = 0.f;
#pragma unroll
        for (int c = 0; c < 32; c++) rt += xt[t][c] * root[c * 32 + d];
        v += rt + bias[d];
        v = v >= 0.f ? v : 0.01f * v;   // LeakyReLU (both spline layers)
        out[n * 32 + d] = v;
        float s = v, s2 = v * v;
        s += __shfl_xor(s, 32); s2 += __shfl_xor(s2, 32);
        if ((tid & 63) < 32) {
            scr2[tid >> 6][d] = s;
            scr2[tid >> 6][32 + d] = s2;
        }
    }
    __syncthreads();
    // replicated stats: spreads atomics over 64 slots (no hot lines)
    if (tid < 64) gAdd(&stats[(blockIdx.x & 63) * 64 + tid], scr2[0][tid] + scr2[1][tid]);
}

// ---------------- K5: BN apply with integrated 64-rep fold ----------------
__global__ void k_bn(const float* __restrict__ tin, const float* __restrict__ stats,
                     const float* __restrict__ gamma, const float* __restrict__ beta,
                     float* __restrict__ xout) {
    __shared__ float fl[64];
    int tid = threadIdx.x;
    if (tid < 64) {
        float s = 0.f;
#pragma unroll 8
        for (int r = 0; r < 64; r++) s += stats[r * 64 + tid];
        fl[tid] = s;
    }
    __syncthreads();
    int i = blockIdx.x * 256 + tid;   // grid exact
    int c = i & 31;
    float mu = fl[c] * (1.f / NN);
    float var = fl[32 + c] * (1.f / NN) - mu * mu;
    float g = gamma[c] * rsqrtf(var + 1e-5f);
    xout[i] = (tin[i] - mu) * g + beta[c];
}
__global__ void k_bn_cvt(const float* __restrict__ tin, const float* __restrict__ stats,
                         const float* __restrict__ gamma, const float* __restrict__ beta,
                         float* __restrict__ xout, unsigned short* __restrict__ xh) {
    __shared__ float fl[64];
    int tid = threadIdx.x;
    if (tid < 64) {
        float s = 0.f;
#pragma unroll 8
        for (int r = 0; r < 64; r++) s += stats[r * 64 + tid];
        fl[tid] = s;
    }
    __syncthreads();
    int i = blockIdx.x * 256 + tid;
    int c = i & 31;
    float mu = fl[c] * (1.f / NN);
    float var = fl[32 + c] * (1.f / NN) - mu * mu;
    float g = gamma[c] * rsqrtf(var + 1e-5f);
    float v = (tin[i] - mu) * g + beta[c];
    xout[i] = v;
    xh[i] = f2bf(v);
}

// ---------------- K6a: NodeFormer pass 1 (two-stage, NO LDS atomics) ----------------
__global__ void __launch_bounds__(256) k_nf1(
        const float* __restrict__ x, const float* __restrict__ wqkv,
        const float* __restrict__ wp, const float* __restrict__ gumbel,
        unsigned short* __restrict__ vh, float* __restrict__ kvg) {
    __shared__ float xl[32 * 33];
    __shared__ __align__(16) float kq[32][8][4];
    __shared__ __align__(16) float vv[32][8][4];
    __shared__ float sqv[32][8];
    __shared__ float gsv[32][8];
    int tid = threadIdx.x;
    int base = blockIdx.x * 32;
#pragma unroll
    for (int r = 0; r < 4; r++) {
        int i = r * 256 + tid;
        int gi = base * 32 + i;
        float v = (gi < NN * 32) ? x[gi] : 0.f;
        xl[(i >> 5) * 33 + (i & 31)] = v;
    }
    __syncthreads();
    int nl = tid >> 3, h = tid & 7;
    int n = base + nl;
    int act = (n < NN) ? 1 : 0;
    const float* xp = &xl[nl * 33];
    float kr0 = 0, kr1 = 0, kr2 = 0, kr3 = 0, vr0 = 0, vr1 = 0, vr2 = 0, vr3 = 0;
#pragma unroll
    for (int c = 0; c < 32; c++) {
        float xc = xp[c];
        const float4 wk4 = *(const float4*)(wqkv + 1024 + c * 32 + h * 4);
        const float4 wv4 = *(const float4*)(wqkv + 2048 + c * 32 + h * 4);
        kr0 += xc * wk4.x; kr1 += xc * wk4.y; kr2 += xc * wk4.z; kr3 += xc * wk4.w;
        vr0 += xc * wv4.x; vr1 += xc * wv4.y; vr2 += xc * wv4.z; vr3 += xc * wv4.w;
    }
    if (act) {
        unsigned lo = (unsigned)f2bf(vr0) | ((unsigned)f2bf(vr1) << 16);
        unsigned hi_ = (unsigned)f2bf(vr2) | ((unsigned)f2bf(vr3) << 16);
        *(uint2*)&vh[n * 32 + h * 4] = make_uint2(lo, hi_);
    }
    const float inv_rt2 = 0.70710678118f;     // 1/DH^0.25
    const float invSqM = 0.17677669529f;      // 1/sqrt(32)
    float x0 = kr0 * inv_rt2, x1 = kr1 * inv_rt2, x2 = kr2 * inv_rt2, x3 = kr3 * inv_rt2;
    float sq = 0.5f * (x0 * x0 + x1 * x1 + x2 * x2 + x3 * x3);
    float gs = act ? (__expf(gumbel[(act ? n : 0) * 8 + h]) * invSqM) : 0.f;
    *(float4*)&kq[nl][h][0] = make_float4(x0, x1, x2, x3);
    *(float4*)&vv[nl][h][0] = make_float4(vr0, vr1, vr2, vr3);
    sqv[nl][h] = sq;
    gsv[nl][h] = gs;
    __syncthreads();
    // stage 2: register accumulation over the block's 32 nodes
    int h2 = tid >> 5, m = tid & 31;
    const float* wph = wp + h2 * 128;
    float w0 = wph[m], w1 = wph[32 + m], w2 = wph[64 + m], w3 = wph[96 + m];
    float ks = 0.f, a0 = 0.f, a1 = 0.f, a2 = 0.f, a3 = 0.f;
#pragma unroll 4
    for (int nn2 = 0; nn2 < 32; nn2++) {
        float4 k4 = *(const float4*)&kq[nn2][h2][0];
        float4 v4 = *(const float4*)&vv[nn2][h2][0];
        float pr = k4.x * w0 + k4.y * w1 + k4.z * w2 + k4.w * w3;
        float phk = __expf(pr - sqv[nn2][h2]) * gsv[nn2][h2];
        ks += phk;
        a0 += phk * v4.x; a1 += phk * v4.y; a2 += phk * v4.z; a3 += phk * v4.w;
    }
    float* kvr = kvg + (blockIdx.x & 7) * 1280;
    gAdd(&kvr[1024 + h2 * 32 + m], ks);
    gAdd(&kvr[0 * 256 + h2 * 32 + m], a0);
    gAdd(&kvr[1 * 256 + h2 * 32 + m], a1);
    gAdd(&kvr[2 * 256 + h2 * 32 + m], a2);
    gAdd(&kvr[3 * 256 + h2 * 32 + m], a3);
}

// ---------------- K6b: NodeFormer pass 2 ----------------
__global__ void __launch_bounds__(256) k_nf2(
        const float* __restrict__ x, const float* __restrict__ wqkv,
        const float* __restrict__ wp, const float* __restrict__ brel,
        const float* __restrict__ wo, const float* __restrict__ bo,
        const float* __restrict__ kvg, const int* __restrict__ rowptr,
        const float2* __restrict__ re2, const unsigned short* __restrict__ vh,
        int do_leaky, float* __restrict__ out, float* __restrict__ stats) {
    __shared__ float xl[32 * 33];
    __shared__ float ylds[32 * 33];
    __shared__ float kvs[1280];
    __shared__ float scr2[4][64];    // per-wave stat slots (no atomics)
    int tid = threadIdx.x;
    int base = blockIdx.x * 32;
#pragma unroll
    for (int r = 0; r < 4; r++) {
        int i = r * 256 + tid;
        int gi = base * 32 + i;
        float v = (gi < NN * 32) ? x[gi] : 0.f;
        xl[(i >> 5) * 33 + (i & 31)] = v;
    }
    // stage kv summary: sum the 8 replicated slots into LDS
    for (int i = tid; i < 1280; i += 256) {
        float s = 0.f;
#pragma unroll
        for (int r = 0; r < 8; r++) s += kvg[r * 1280 + i];
        kvs[i] = s;
    }
    __syncthreads();
    int nl = tid >> 3, h = tid & 7;
    int n = base + nl;
    int act = (n < NN) ? 1 : 0;
    int nc = act ? n : (NN - 1);
    const float* xp = &xl[nl * 33];
    float q0 = 0, q1 = 0, q2 = 0, q3 = 0;
#pragma unroll
    for (int c = 0; c < 32; c++) {
        float xc = xp[c];
        const float4 wq4 = *(const float4*)(wqkv + c * 32 + h * 4);
        q0 += xc * wq4.x; q1 += xc * wq4.y; q2 += xc * wq4.z; q3 += xc * wq4.w;
    }
    const float inv_rt2 = 0.70710678118f;
    const float invSqM = 0.17677669529f;
    float x0 = q0 * inv_rt2, x1 = q1 * inv_rt2, x2 = q2 * inv_rt2, x3 = q3 * inv_rt2;
    float sq = 0.5f * (x0 * x0 + x1 * x1 + x2 * x2 + x3 * x3);
    const float* wph = wp + h * 128;
    float den = 0.f, n0 = 0.f, n1 = 0.f, n2 = 0.f, n3 = 0.f;
    for (int mm = 0; mm < 32; mm++) {
        int m = (mm + 4 * h) & 31;            // h-stagger: LDS bank-clean
        float pr = x0 * wph[m] + x1 * wph[32 + m] + x2 * wph[64 + m] + x3 * wph[96 + m];
        float phq = __expf(pr - sq) * invSqM;
        den += phq * kvs[1024 + h * 32 + m];
        n0 += phq * kvs[0 * 256 + h * 32 + m];
        n1 += phq * kvs[1 * 256 + h * 32 + m];
        n2 += phq * kvs[2 * 256 + h * 32 + m];
        n3 += phq * kvs[3 * 256 + h * 32 + m];
    }
    float inv = 1.f / (den + 1e-6f);
    float y0 = n0 * inv, y1 = n1 * inv, y2 = n2 * inv, y3 = n3 * inv;
    // relational bias: 8-deep shfl-batched bf16 vh row gathers
    float r0 = 0, r1 = 0, r2 = 0, r3 = 0;
    int rs = rowptr[nc];
    int re = act ? rowptr[nc + 1] : rs;
    int lb = (tid & 63) & 56;                 // wave-lane base of this node's 8-group
    for (int e0 = rs; e0 < re; e0 += 8) {
        int cnt = re - e0; if (cnt > 8) cnt = 8;
        float2 med = make_float2(__int_as_float(0), 0.f);
        if (h < cnt) med = re2[e0 + h];
        int msrc = __float_as_int(med.x);
        uint2 xs4[8];
        float nrj[8];
#pragma unroll
        for (int jj = 0; jj < 8; jj++) {
            int s   = __shfl(msrc, lb + jj);
            float nr = __shfl(med.y, lb + jj);
            nrj[jj] = (jj < cnt) ? nr : 0.f;
            int sc  = (jj < cnt) ? s : 0;
            xs4[jj] = *(const uint2*)&vh[sc * 32 + h * 4];
        }
#pragma unroll
        for (int jj = 0; jj < 8; jj++) {
            uint2 u = xs4[jj];
            r0 += nrj[jj] * __uint_as_float(u.x << 16);
            r1 += nrj[jj] * __uint_as_float(u.x & 0xFFFF0000u);
            r2 += nrj[jj] * __uint_as_float(u.y << 16);
            r3 += nrj[jj] * __uint_as_float(u.y & 0xFFFF0000u);
        }
    }
    float sg = 1.f / (1.f + __expf(-brel[h]));
    y0 += sg * r0; y1 += sg * r1; y2 += sg * r2; y3 += sg * r3;
    ylds[nl * 33 + h * 4 + 0] = y0;
    ylds[nl * 33 + h * 4 + 1] = y1;
    ylds[nl * 33 + h * 4 + 2] = y2;
    ylds[nl * 33 + h * 4 + 3] = y3;
    __syncthreads();
    // output projection: thread (nl,h) computes z[d = h*4 .. h*4+3]
    const float* yp = &ylds[nl * 33];
    const float4 b4 = *(const float4*)(bo + h * 4);
    float z0 = b4.x, z1 = b4.y, z2 = b4.z, z3 = b4.w;
#pragma unroll
    for (int j = 0; j < 32; j++) {
        float yv = yp[j];
        const float4 w4 = *(const float4*)(wo + j * 32 + h * 4);
        z0 += yv * w4.x; z1 += yv * w4.y; z2 += yv * w4.z; z3 += yv * w4.w;
    }
    if (do_leaky) {
        z0 = z0 >= 0.f ? z0 : 0.01f * z0;
        z1 = z1 >= 0.f ? z1 : 0.01f * z1;
        z2 = z2 >= 0.f ? z2 : 0.01f * z2;
        z3 = z3 >= 0.f ? z3 : 0.01f * z3;
    }
    if (act) *(float4*)&out[n * 32 + h * 4] = make_float4(z0, z1, z2, z3);
    // BN stats: shfl-reduce over nl within wave; lanes 0-7 store to per-wave slots
    int wv = tid >> 6;
    float sv[4] = {act ? z0 : 0.f, act ? z1 : 0.f, act ? z2 : 0.f, act ? z3 : 0.f};
#pragma unroll
    for (int j = 0; j < 4; j++) {
        float s = sv[j], s2 = sv[j] * sv[j];
        s += __shfl_xor(s, 8);  s2 += __shfl_xor(s2, 8);
        s += __shfl_xor(s, 16); s2 += __shfl_xor(s2, 16);
        s += __shfl_xor(s, 32); s2 += __shfl_xor(s2, 32);
        if (((tid & 63) >> 3) == 0) {
            scr2[wv][h * 4 + j] = s;
            scr2[wv][32 + h * 4 + j] = s2;
        }
    }
    __syncthreads();
    if (tid < 64)
        gAdd(&stats[(blockIdx.x & 63) * 64 + tid],
             scr2[0][tid] + scr2[1][tid] + scr2[2][tid] + scr2[3][tid]);
}

extern "C" void kernel_launch(void* const* d_in, const int* in_sizes, int n_in,
                              void* d_out, int out_size, void* d_ws, size_t ws_size,
                              hipStream_t stream) {
    (void)in_sizes; (void)n_in; (void)out_size; (void)ws_size;
    const float* x_in  = (const float*)d_in[0];
    const int*   ei    = (const int*)d_in[1];
    const float* attr  = (const float*)d_in[2];
    const float* wsp1  = (const float*)d_in[3];
    const float* root1 = (const float*)d_in[4];
    const float* bias1 = (const float*)d_in[5];
    const float* wsp2  = (const float*)d_in[6];
    const float* root2 = (const float*)d_in[7];
    const float* bias2 = (const float*)d_in[8];
    const float* gam   = (const float*)d_in[9];
    const float* bet   = (const float*)d_in[10];
    const float* w1qkv = (const float*)d_in[11];
    const float* w1p   = (const float*)d_in[12];
    const float* b1rel = (const float*)d_in[13];
    const float* w1o   = (const float*)d_in[14];
    const float* b1o   = (const float*)d_in[15];
    const float* gum1  = (const float*)d_in[16];
    const float* w2qkv = (const float*)d_in[17];
    const float* w2p   = (const float*)d_in[18];
    const float* b2rel = (const float*)d_in[19];
    const float* w2o   = (const float*)d_in[20];
    const float* b2o   = (const float*)d_in[21];
    const float* gum2  = (const float*)d_in[22];
    float* outp = (float*)d_out;

    char* wsb = (char*)d_ws;
    size_t off = 0;
    auto carve = [&](size_t bytes) -> char* {
        char* p = wsb + off;
        off += (bytes + 255) & ~(size_t)255;
        return p;
    };
    int*    cnt    = (int*)carve((size_t)NN * 4);
    float*  kvg1   = (float*)carve(8 * 1280 * 4);
    float*  kvg2   = (float*)carve(8 * 1280 * 4);
    float*  stats  = (float*)carve(4 * 64 * 64 * 4);    // [layer][64 reps][64]
    size_t zero_bytes = off;                     // everything above must start at 0
    int*    rowptr = (int*)carve((size_t)(NN + 1) * 4);
    int*    fill   = (int*)carve((size_t)NN * 4);
    float*  degf   = (float*)carve((size_t)NN * 4);
    int*    sedgeP = (int*)carve((size_t)NE * 32);
    float2* re2    = (float2*)carve((size_t)NE * 8);
    unsigned short* xh0 = (unsigned short*)carve((size_t)NN * 32 * 2);
    unsigned short* xah = (unsigned short*)carve((size_t)NN * 32 * 2);
    unsigned short* vh  = (unsigned short*)carve((size_t)NN * 32 * 2);
    float*  xa     = (float*)carve((size_t)NN * 32 * 4);
    float*  xb     = (float*)carve((size_t)NN * 32 * 4);
    float*  tb     = (float*)carve((size_t)NN * 32 * 4);

    hipMemsetAsync(d_ws, 0, zero_bytes, stream);
    k_hist<<<NE / 256, 256, 0, stream>>>(ei, cnt);
    k_scan<<<1, 1024, 0, stream>>>(cnt, rowptr, fill, degf);
    k_scatter<<<NE / 256, 256, 0, stream>>>(ei, attr, degf, fill, sedgeP, re2);
    k_cvt<<<NN * 32 / 256, 256, 0, stream>>>(x_in, xh0);

    // layer 1: spline + leaky + BN0 (BN emits bf16 for layer-2 gather)
    k_spline<<<NN / 4, 256, 0, stream>>>(x_in, xh0, rowptr, sedgeP, degf, wsp1, root1, bias1, tb, stats);
    k_bn_cvt<<<NN * 32 / 256, 256, 0, stream>>>(tb, stats, gam, bet, xa, xah);
    // layer 2: spline + leaky + BN1
    k_spline<<<NN / 4, 256, 0, stream>>>(xa, xah, rowptr, sedgeP, degf, wsp2, root2, bias2, tb, stats + 4096);
    k_bn<<<NN * 32 / 256, 256, 0, stream>>>(tb, stats + 4096, gam + 32, bet + 32, xb);

    int nfgrid = (NN + 31) / 32;
    // layer 3: nodeformer1 + leaky + BN2
    k_nf1<<<nfgrid, 256, 0, stream>>>(xb, w1qkv, w1p, gum1, vh, kvg1);
    k_nf2<<<nfgrid, 256, 0, stream>>>(xb, w1qkv, w1p, b1rel, w1o, b1o, kvg1, rowptr, re2,
                                      vh, 1, tb, stats + 8192);
    k_bn<<<NN * 32 / 256, 256, 0, stream>>>(tb, stats + 8192, gam + 64, bet + 64, xa);
    // layer 4: nodeformer2 + BN3 (no leaky)
    k_nf1<<<nfgrid, 256, 0, stream>>>(xa, w2qkv, w2p, gum2, vh, kvg2);
    k_nf2<<<nfgrid, 256, 0, stream>>>(xa, w2qkv, w2p, b2rel, w2o, b2o, kvg2, rowptr, re2,
                                      vh, 0, tb, stats + 12288);
    k_bn<<<NN * 32 / 256, 256, 0, stream>>>(tb, stats + 12288, gam + 96, bet + 96, outp);
}